// Round 1
// baseline (12205.440 us; speedup 1.0000x reference)
//
#include <hip/hip_runtime.h>
#include <hip/hip_bf16.h>

// ============================================================================
// CategoricalGraphAtt on MI355X.
// R6: collapse the 4 independent batch-groups of the GRU recurrence into ONE
// (M=100 rows per WG, 64 WGs = 1 per slice). Same weights-in-register
// structure, same 16-producer fan-in per wave, but 4x fewer pollers, 4x fewer
// flag writes, 4x fewer simultaneous write-through bursts, and 4x fewer WGs in
// the per-step straggler max. fp32 h-state moved from LDS into registers.
// hist layout is now [t][slice 64][row 100][j 16]; att_pool gather updated.
// ============================================================================

typedef __bf16 bf16x8 __attribute__((ext_vector_type(8)));
typedef float  floatx4 __attribute__((ext_vector_type(4)));
typedef int    intx4  __attribute__((ext_vector_type(4)));

struct US8 { unsigned short u[8]; };

__device__ __forceinline__ unsigned short f2bf(float f) {
  unsigned u = __builtin_bit_cast(unsigned, f);
  u += 0x7fffu + ((u >> 16) & 1u);           // RNE
  return (unsigned short)(u >> 16);
}
__device__ __forceinline__ float bf2f(unsigned short h) {
  return __builtin_bit_cast(float, ((unsigned)h) << 16);
}
__device__ __forceinline__ float sigm(float x) { return 1.f / (1.f + __expf(-x)); }

// raw barrier: LDS-only ordering (no vmcnt drain)
__device__ __forceinline__ void bar_lds() {
  asm volatile("s_waitcnt lgkmcnt(0)" ::: "memory");
  __builtin_amdgcn_s_barrier();
  asm volatile("" ::: "memory");
}

// ---------------- workspace layout (bytes) ----------------
static const size_t OF_XBF   = 0;                 // bf16 x [100][512][256]   26,214,400
static const size_t OF_HIST  = 26214400;          // bf16 h_hist [513][64 s][100 r][16 j] 105,062,400
static const size_t OF_ENCW  = 131277824;         // bf16 enc_att_W [512][512] 524,288
static const size_t OF_V     = 131802112;         // f32 v [100][1024]
static const size_t OF_HIN   = 132211712;         // f32 inner-GAT h
static const size_t OF_IEMB  = 132621312;         // f32 inner_emb
static const size_t OF_CATV  = 133030912;         // f32 cat_vec (pooled) [5][1024]
static const size_t OF_CATH  = 133051392;         // f32 cat-GAT h
static const size_t OF_CATO  = 133071872;         // f32 cat GAT out
static const size_t OF_FBUF  = 133092352;         // f32 fusion input [100][3072]
static const size_t OF_FOUT  = 134321152;         // f32 fusion output [100][1024]
static const size_t OF_FLAGS = 134730752;         // int flags[64 cwg][4 wave][16] = 16,384 (65,536 reserved)

// ---------------- fp32 -> bf16 convert ----------------
__global__ void f2bf_kernel(const float* __restrict__ src, unsigned short* __restrict__ dst, int n4) {
  int i = blockIdx.x * 256 + threadIdx.x;
  if (i < n4) {
    float4 v = ((const float4*)src)[i];
    ushort4 o;
    o.x = f2bf(v.x); o.y = f2bf(v.y); o.z = f2bf(v.z); o.w = f2bf(v.w);
    ((ushort4*)dst)[i] = o;
  }
}

// ---------------- GRU epilogue: one (col l, row-quad q) unit ----------------
// ghp blocks: [(w*7+mt)*3+gg][16 col * 20 stride], gates gg: 0=r 1=z 2=hn (w<4) / xn (w=4)
__device__ __forceinline__ void gru_epi(int u, floatx4& h4, const float* ghp,
                                        const float* biasl, unsigned short* hb16) {
  int l = u & 15, q = u >> 4;              // l: hidden col, q: row-quad (rows q*4..q*4+3)
  int mt2 = q >> 2, rr0 = (q & 3) * 4;
  const float* g0 = ghp + (size_t)(mt2 * 3) * 320 + l * 20 + rr0;
  floatx4 ghr  = *(const floatx4*)(g0);
  floatx4 ghz  = *(const floatx4*)(g0 + 320);
  floatx4 ghnh = *(const floatx4*)(g0 + 640);
  #pragma unroll
  for (int ww = 1; ww < 4; ww++) {
    const float* gq = g0 + ww * (21 * 320);
    ghr  += *(const floatx4*)(gq);
    ghz  += *(const floatx4*)(gq + 320);
    ghnh += *(const floatx4*)(gq + 640);
  }
  const float* gx = g0 + 4 * (21 * 320);   // wave-4 (x-part) block
  ghr += *(const floatx4*)(gx);
  ghz += *(const floatx4*)(gx + 320);
  floatx4 ghnx = *(const floatx4*)(gx + 640);
  float br = biasl[l], bz = biasl[16 + l], bnh = biasl[32 + l], bnx = biasl[48 + l];
  #pragma unroll
  for (int j = 0; j < 4; j++) {
    float r = sigm(ghr[j] + br);
    float z = sigm(ghz[j] + bz);
    float nv = ghnx[j] + bnx + r * (ghnh[j] + bnh);
    nv = fminf(fmaxf(nv, -15.f), 15.f);
    float e2 = __expf(-2.f * nv);
    float n = (1.f - e2) / (1.f + e2);
    float hn = (1.f - z) * n + z * h4[j];
    h4[j] = hn;
    hb16[(q * 4 + j) * 16 + l] = f2bf(hn);
  }
}

// ---------------- persistent GRU recurrence ----------------
// grid 64 = 64 slices (16 j each), M = all 100 rows. block 320 (5 waves).
// waves 0-3: k-steps 8w..8w+8 of h-part (K=1024); wave 4: x-part (K=256) +
// the whole store/flag tail.
// hist layout per step: [slice s(64)][row(100)][16 j] bf16 (1600 shorts/slice).
// LDS: ghp [105 blk][16 col * 20] f32 @0 (134,400; overlays Bw 122,880 init
//      scratch) | hb16 [100][16] bf16 @134,400 | bias [4][16] @137,600.
#define GRU_LDS 137856
__global__ void __launch_bounds__(320, 2) gru_recur(
    const unsigned short* __restrict__ xbf,
    const float* __restrict__ Whh, const float* __restrict__ Wih,
    const float* __restrict__ bih, const float* __restrict__ bhh,
    unsigned short* hist, int* flags)
{
  extern __shared__ char smem[];
  float* ghp  = (float*)smem;                        // [105][320] partials (post-init)
  unsigned short* hb16 = (unsigned short*)(smem + 134400);  // [100][16] staged h'
  float* biasl = (float*)(smem + 137600);            // [4][16]: r,z,hn,xn
  unsigned short* Bw  = (unsigned short*)smem;       // init-only gather scratch

  const int tid  = threadIdx.x;
  const int lane = tid & 63;
  const int w    = tid >> 6;       // 0..4
  const int s    = blockIdx.x;     // slice 0..63
  const int myq  = s >> 4;         // producer quarter

  // ---- gather B (Whh/Wih rows for this slice) into LDS in frag order ----
  for (int o = tid; o < 7680; o += 320) {
    int kk, ln; const float* sp; unsigned short* dst;
    if (o < 5120) {
      int q = o >= 2560; int rem = o - q * 2560;
      kk = rem >> 6; ln = rem & 63;
      int l = ln & 15, ksub = ln >> 4, j = s * 16 + l;
      int k = kk * 32 + ksub * 8;
      sp = (k < 1024) ? (Whh + (size_t)(q * 1024 + j) * 1024 + k)
                      : (Wih + (size_t)(q * 1024 + j) * 256 + (k - 1024));
      dst = Bw + ((size_t)((q * 40 + kk) * 64 + ln)) * 8;
    } else if (o < 7168) {
      int o2 = o - 5120; kk = o2 >> 6; ln = o2 & 63;
      int l = ln & 15, ksub = ln >> 4, j = s * 16 + l;
      sp = Whh + (size_t)(2048 + j) * 1024 + kk * 32 + ksub * 8;
      dst = Bw + (size_t)(5120 + kk * 64 + ln) * 8;
    } else {
      int o3 = o - 7168; kk = o3 >> 6; ln = o3 & 63;
      int l = ln & 15, ksub = ln >> 4, j = s * 16 + l;
      sp = Wih + (size_t)(2048 + j) * 256 + kk * 32 + ksub * 8;
      dst = Bw + (size_t)(7168 + kk * 64 + ln) * 8;
    }
    float4 f0 = *(const float4*)sp;
    float4 f1 = *(const float4*)(sp + 4);
    dst[0] = f2bf(f0.x); dst[1] = f2bf(f0.y); dst[2] = f2bf(f0.z); dst[3] = f2bf(f0.w);
    dst[4] = f2bf(f1.x); dst[5] = f2bf(f1.y); dst[6] = f2bf(f1.z); dst[7] = f2bf(f1.w);
  }
  if (tid < 16) {
    int j = s * 16 + tid;
    biasl[tid]      = bih[j]        + bhh[j];
    biasl[16 + tid] = bih[1024 + j] + bhh[1024 + j];
    biasl[32 + tid] = bhh[2048 + j];
    biasl[48 + tid] = bih[2048 + j];
  }
  __syncthreads();

  // ---- hoist B fragments (persist across all 512 steps) ----
  bf16x8 Breg[24];
  #pragma unroll
  for (int lk = 0; lk < 8; lk++) {
    int kk = w * 8 + lk;
    Breg[lk * 3 + 0] = __builtin_bit_cast(bf16x8, *(const intx4*)(Bw + (size_t)((kk)      * 64 + lane) * 8));
    Breg[lk * 3 + 1] = __builtin_bit_cast(bf16x8, *(const intx4*)(Bw + (size_t)((40 + kk) * 64 + lane) * 8));
    const unsigned short* np = (w < 4)
        ? (Bw + (size_t)(5120 + kk * 64 + lane) * 8)
        : (Bw + (size_t)(7168 + (kk - 32) * 64 + lane) * 8);
    Breg[lk * 3 + 2] = __builtin_bit_cast(bf16x8, *(const intx4*)np);
  }
  __syncthreads();   // ghp overlays Bw: no partial writes before all hoists done

  // A-operand addressing.
  // h (slice-major): slice = 2*kk + (lane>>5); elem = slice*1600 + row*16 + ((lane>>4)&1)*8
  // x (row-major): xbf + row*512*256 + t*256 + (kk-32)*32 + (lane>>4)*8
  const int kf_h = ((lane >> 4) & 1) * 8;
  const int kf_x = (lane >> 4) * 8;
  int baseA[7], rowx[7];
  #pragma unroll
  for (int mt = 0; mt < 7; mt++) {
    int m = mt * 16 + (lane & 15);
    int bb = (m < 100) ? m : 99;           // clamp pad rows
    baseA[mt] = (lane >> 5) * 1600 + bb * 16 + kf_h;
    rowx[mt]  = bb * 131072;               // 512*256 shorts per row
  }

  const int* pollline = flags + (s * 4 + w) * 16;      // private per (WG, wave)
  floatx4 h4a = {0.f, 0.f, 0.f, 0.f};                  // fp32 h state in regs
  floatx4 h4b = {0.f, 0.f, 0.f, 0.f};                  // (second unit, tid<80)

  for (int t = 0; t < 512; t++) {
    // ---- wait for this wave's k-quarter producers (private line, no sleep) ----
    if (w < 4) {
      for (;;) {
        int f = __hip_atomic_load(pollline + (lane & 15), __ATOMIC_RELAXED, __HIP_MEMORY_SCOPE_AGENT);
        if (__all(f >= t)) break;
      }
      asm volatile("" ::: "memory");   // no hoisting of h loads above the spin
    }

    const unsigned short* hrow = hist + (size_t)t * 102400;
    const unsigned short* xrow = xbf + t * 256;
    floatx4 acc[7][3];
    #pragma unroll
    for (int mt = 0; mt < 7; mt++)
      #pragma unroll
      for (int gg = 0; gg < 3; gg++) acc[mt][gg] = floatx4{0.f, 0.f, 0.f, 0.f};

    #pragma unroll
    for (int lk = 0; lk < 8; lk++) {
      int kk = w * 8 + lk;
      #pragma unroll
      for (int mt = 0; mt < 7; mt++) {
        const unsigned short* ap = (w < 4)
            ? (hrow + baseA[mt] + kk * 3200)
            : (xrow + rowx[mt] + (kk - 32) * 32 + kf_x);
        bf16x8 a = __builtin_bit_cast(bf16x8, *(const intx4*)ap);
        acc[mt][0] = __builtin_amdgcn_mfma_f32_16x16x32_bf16(a, Breg[lk * 3 + 0], acc[mt][0], 0, 0, 0);
        acc[mt][1] = __builtin_amdgcn_mfma_f32_16x16x32_bf16(a, Breg[lk * 3 + 1], acc[mt][1], 0, 0, 0);
        acc[mt][2] = __builtin_amdgcn_mfma_f32_16x16x32_bf16(a, Breg[lk * 3 + 2], acc[mt][2], 0, 0, 0);
      }
    }

    // partials -> LDS: [block][col l * 20][rows at q*4] (float4 per quad)
    {
      int pb = (lane & 15) * 20 + (lane >> 4) * 4;
      #pragma unroll
      for (int mt = 0; mt < 7; mt++)
        #pragma unroll
        for (int gg = 0; gg < 3; gg++)
          *(floatx4*)(ghp + (size_t)((w * 7 + mt) * 3 + gg) * 320 + pb) = acc[mt][gg];
    }
    bar_lds();   // (1) partials visible

    // ---- epilogue: 400 (col, row-quad) units over 320 threads ----
    gru_epi(tid, h4a, ghp, biasl, hb16);
    if (tid < 80) gru_epi(tid + 320, h4b, ghp, biasl, hb16);

    bar_lds();   // (2) hb16 visible to wave 4; ghp free for next MFMA round

    // ---- wave 4: contiguous 16B write-through stores + ack + flag fan-out ----
    if (w == 4) {
      unsigned long long hbase = (unsigned long long)(hist + (size_t)(t + 1) * 102400
                                                      + (size_t)s * 1600);
      #pragma unroll
      for (int i = 0; i < 3; i++) {
        int c = lane + 64 * i;             // 200 chunks of 16B (100 rows x 2 halves)
        intx4 d = *(const intx4*)(hb16 + c * 8);
        asm volatile("global_store_dwordx4 %0, %1, off sc0 sc1"
                     :: "v"(hbase + (unsigned long long)c * 16), "v"(d) : "memory");
      }
      if (lane < 8) {
        int c = 192 + lane;
        intx4 d = *(const intx4*)(hb16 + c * 8);
        asm volatile("global_store_dwordx4 %0, %1, off sc0 sc1"
                     :: "v"(hbase + (unsigned long long)c * 16), "v"(d) : "memory");
      }
      if (t < 511) {
        asm volatile("s_waitcnt vmcnt(0)" ::: "memory");   // h' at MALL before flags
        __hip_atomic_store(flags + (lane * 4 + myq) * 16 + (s & 15), t + 1,
                           __ATOMIC_RELAXED, __HIP_MEMORY_SCOPE_AGENT);
      }
    }
    // waves 0-3 fall through to the next poll immediately.
  }
}

// ---------------- fused time attention ----------------
// grid 1600 (one 64-col block of n'=(b*1024+d)), block 512 (8 waves).
#define ATT_LDS 68096
__global__ void __launch_bounds__(512) att_pool(
    const unsigned short* __restrict__ hist,   // slots 1..512, slice-major
    const unsigned short* __restrict__ encw,   // bf16 [512][512]
    const float* __restrict__ encb,
    float* __restrict__ vout)
{
  extern __shared__ char smem[];
  unsigned short* Bs = (unsigned short*)smem;          // [16ks][4nt][64lane][8]
  float* red  = (float*)(smem + 65536);                // [8][64]
  float* cmax = (float*)(smem + 65536 + 2048);
  float* csum = (float*)(smem + 65536 + 2048 + 256);

  const int tid = threadIdx.x, w = tid >> 6, lane = tid & 63;
  const int q = lane >> 4, col = lane & 15;
  const int n0 = blockIdx.x * 64;
  const int bA = n0 >> 10, d0 = n0 & 1023;

  // stage hs tile (slice-major gather, transposed scatter into frag layout)
  for (int ii = 0; ii < 8; ii++) {
    int c = tid + 512 * ii;
    int t = c >> 3, dd = c & 7;
    int sA = (d0 >> 4) + (dd >> 1), hsA = dd & 1;
    intx4 li = *(const intx4*)(hist + (size_t)(t + 1) * 102400
                             + (size_t)(sA * 1600 + bA * 16 + hsA * 8));
    US8 u8 = __builtin_bit_cast(US8, li);
    int kstep = t >> 5, ksub = (t >> 3) & 3, i = t & 7;
    int ntile = dd >> 1, nc0 = (dd & 1) * 8;
    unsigned short* dst = Bs + ((size_t)((kstep * 4 + ntile) * 64 + ksub * 16 + nc0)) * 8 + i;
    #pragma unroll
    for (int jj = 0; jj < 8; jj++) dst[jj * 8] = u8.u[jj];
  }
  __syncthreads();

  floatx4 acc[4][4];
  #pragma unroll
  for (int mi = 0; mi < 4; mi++)
    #pragma unroll
    for (int ni = 0; ni < 4; ni++) acc[mi][ni] = floatx4{0.f, 0.f, 0.f, 0.f};

  #pragma unroll 2
  for (int kk = 0; kk < 16; kk++) {
    int tch = kk * 32 + q * 8;
    bf16x8 af[4];
    #pragma unroll
    for (int mi = 0; mi < 4; mi++) {
      int u = (w * 4 + mi) * 16 + col;
      af[mi] = __builtin_bit_cast(bf16x8, *(const intx4*)(encw + (size_t)u * 512 + tch));
    }
    #pragma unroll
    for (int ni = 0; ni < 4; ni++) {
      bf16x8 bf = __builtin_bit_cast(bf16x8, *(const intx4*)(Bs + (size_t)((kk * 4 + ni) * 64 + lane) * 8));
      #pragma unroll
      for (int mi = 0; mi < 4; mi++)
        acc[mi][ni] = __builtin_amdgcn_mfma_f32_16x16x32_bf16(af[mi], bf, acc[mi][ni], 0, 0, 0);
    }
  }

  // + row bias
  #pragma unroll
  for (int mi = 0; mi < 4; mi++) {
    int ub = (w * 4 + mi) * 16 + q * 4;
    float b0 = encb[ub], b1 = encb[ub + 1], b2 = encb[ub + 2], b3 = encb[ub + 3];
    #pragma unroll
    for (int ni = 0; ni < 4; ni++) {
      acc[mi][ni][0] += b0; acc[mi][ni][1] += b1; acc[mi][ni][2] += b2; acc[mi][ni][3] += b3;
    }
  }
  // column max
  #pragma unroll
  for (int ni = 0; ni < 4; ni++) {
    float m = -1e30f;
    #pragma unroll
    for (int mi = 0; mi < 4; mi++)
      #pragma unroll
      for (int r = 0; r < 4; r++) m = fmaxf(m, acc[mi][ni][r]);
    m = fmaxf(m, __shfl_xor(m, 16)); m = fmaxf(m, __shfl_xor(m, 32));
    red[w * 64 + ni * 16 + col] = m;
  }
  __syncthreads();
  if (tid < 64) {
    float m = red[tid];
    for (int w2 = 1; w2 < 8; w2++) m = fmaxf(m, red[w2 * 64 + tid]);
    cmax[tid] = m;
  }
  __syncthreads();
  // exp + column sum
  #pragma unroll
  for (int ni = 0; ni < 4; ni++) {
    float cm = cmax[ni * 16 + col];
    float sum = 0.f;
    #pragma unroll
    for (int mi = 0; mi < 4; mi++)
      #pragma unroll
      for (int r = 0; r < 4; r++) {
        float e = __expf(acc[mi][ni][r] - cm);
        acc[mi][ni][r] = e; sum += e;
      }
    sum += __shfl_xor(sum, 16); sum += __shfl_xor(sum, 32);
    red[w * 64 + ni * 16 + col] = sum;
  }
  __syncthreads();
  if (tid < 64) {
    float sm = 0.f;
    for (int w2 = 0; w2 < 8; w2++) sm += red[w2 * 64 + tid];
    csum[tid] = sm;
  }
  __syncthreads();
  // weighted sum of hs
  #pragma unroll
  for (int ni = 0; ni < 4; ni++) {
    float p = 0.f;
    #pragma unroll
    for (int mi = 0; mi < 4; mi++) {
      int u0 = (w * 4 + mi) * 16 + q * 4;
      int ks = u0 >> 5, ksb = (u0 >> 3) & 3, i0 = u0 & 7;
      const unsigned short* hp = Bs + (size_t)((ks * 4 + ni) * 64 + ksb * 16 + col) * 8 + i0;
      p += acc[mi][ni][0] * bf2f(hp[0]) + acc[mi][ni][1] * bf2f(hp[1])
         + acc[mi][ni][2] * bf2f(hp[2]) + acc[mi][ni][3] * bf2f(hp[3]);
    }
    p += __shfl_xor(p, 16); p += __shfl_xor(p, 32);
    red[w * 64 + ni * 16 + col] = p;
  }
  __syncthreads();
  if (tid < 64) {
    float p = 0.f;
    for (int w2 = 0; w2 < 8; w2++) p += red[w2 * 64 + tid];
    vout[n0 + tid] = p / csum[tid];
  }
}

// ---------------- small fp32 GEMM: C(M,N) = A(M,K) @ B(N,K)^T [+bias][+relu] ----------------
__global__ void gemm_bt(const float* __restrict__ A, const float* __restrict__ B,
                        float* __restrict__ C, int M, int N, int K,
                        const float* __restrict__ bias, int relu)
{
  __shared__ float Al[16][33];
  __shared__ float Bl[64][33];
  int tx = threadIdx.x;
  int nb = blockIdx.x, mb = blockIdx.y;
  int n = nb * 64 + (tx & 63);
  int mq = tx >> 6;
  float acc[4] = {0.f, 0.f, 0.f, 0.f};
  for (int k0 = 0; k0 < K; k0 += 32) {
    for (int e = tx; e < 512; e += 256) {
      int r = e >> 5, c = e & 31; int m = mb * 16 + r;
      Al[r][c] = (m < M) ? A[(size_t)m * K + k0 + c] : 0.f;
    }
    for (int e = tx; e < 2048; e += 256) {
      int r = e >> 5, c = e & 31;
      Bl[r][c] = B[(size_t)(nb * 64 + r) * K + k0 + c];
    }
    __syncthreads();
    int nn = tx & 63;
    #pragma unroll 8
    for (int c = 0; c < 32; c++) {
      float bv = Bl[nn][c];
      #pragma unroll
      for (int i = 0; i < 4; i++) acc[i] += Al[mq * 4 + i][c] * bv;
    }
    __syncthreads();
  }
  #pragma unroll
  for (int i = 0; i < 4; i++) {
    int m = mb * 16 + mq * 4 + i;
    if (m < M && n < N) {
      float r = acc[i] + (bias ? bias[n] : 0.f);
      if (relu) r = fmaxf(r, 0.f);
      C[(size_t)m * N + n] = r;
    }
  }
}

// ---------------- GAT attention (complete graph + self loops within each block of NN nodes) ----------------
template <int NN>
__global__ void gat_att(const float* __restrict__ h, const float* __restrict__ asrc,
                        const float* __restrict__ adst, const float* __restrict__ bias,
                        float* __restrict__ out)
{
  __shared__ float asd[2][NN];
  __shared__ float P[NN][NN];
  int c = blockIdx.x, tx = threadIdx.x;
  int wid = tx >> 6, lane = tx & 63;
  for (int idx = wid; idx < 2 * NN; idx += 4) {
    int which = idx >= NN; int j = which ? idx - NN : idx;
    const float* av = which ? adst : asrc;
    float p = 0.f;
    for (int k = lane; k < 1024; k += 64) p += h[(size_t)(c * NN + j) * 1024 + k] * av[k];
    for (int m = 32; m; m >>= 1) p += __shfl_xor(p, m);
    if (lane == 0) asd[which][j] = p;
  }
  __syncthreads();
  if (tx < NN) {
    int i = tx; float mx = -1e30f; float e[NN];
    #pragma unroll
    for (int j = 0; j < NN; j++) {
      float x = asd[0][j] + asd[1][i];
      x = (x < 0.f) ? 0.2f * x : x;
      e[j] = x; mx = fmaxf(mx, x);
    }
    float s = 0.f;
    #pragma unroll
    for (int j = 0; j < NN; j++) { e[j] = __expf(e[j] - mx); s += e[j]; }
    #pragma unroll
    for (int j = 0; j < NN; j++) P[i][j] = e[j] / s;
  }
  __syncthreads();
  for (int ee = tx; ee < NN * 1024; ee += 256) {
    int i = ee >> 10, d = ee & 1023;
    float s = 0.f;
    #pragma unroll
    for (int j = 0; j < NN; j++) s += P[i][j] * h[(size_t)(c * NN + j) * 1024 + d];
    out[(size_t)(c * NN + i) * 1024 + d] = s + bias[d];
  }
}

// ---------------- stock->category pooling attention ----------------
__global__ void pool_att(const float* __restrict__ v, const float* __restrict__ pW,
                         const float* __restrict__ pb, float* __restrict__ catv)
{
  __shared__ float W[400]; __shared__ float bsh[20];
  int tx = threadIdx.x;
  for (int i = tx; i < 400; i += 256) W[i] = pW[i];
  if (tx < 20) bsh[tx] = pb[tx];
  __syncthreads();
  int gid = blockIdx.x * 256 + tx;
  int c = gid >> 10, d = gid & 1023;
  float vals[20];
  #pragma unroll
  for (int t = 0; t < 20; t++) vals[t] = v[(size_t)(c * 20 + t) * 1024 + d];
  float wv[20]; float mx = -1e30f;
  #pragma unroll
  for (int u = 0; u < 20; u++) {
    float s = bsh[u];
    #pragma unroll
    for (int t = 0; t < 20; t++) s += vals[t] * W[u * 20 + t];
    wv[u] = s; mx = fmaxf(mx, s);
  }
  float sum = 0.f, out = 0.f;
  #pragma unroll
  for (int u = 0; u < 20; u++) { float e = __expf(wv[u] - mx); sum += e; out += e * vals[u]; }
  catv[gid] = out / sum;
}

// ---------------- fusion concat ----------------
__global__ void concat_kernel(const float* __restrict__ v, const float* __restrict__ cato,
                              const float* __restrict__ iemb, float* __restrict__ F)
{
  int gid = blockIdx.x * 256 + threadIdx.x;
  if (gid < 307200) {
    int i = gid / 3072;
    int k = gid - i * 3072;
    float r;
    if (k < 1024)       r = v[(size_t)i * 1024 + k];
    else if (k < 2048)  r = cato[(size_t)(i / 20) * 1024 + (k - 1024)];
    else                r = iemb[(size_t)i * 1024 + (k - 2048)];
    F[gid] = r;
  }
}

// ---------------- output heads ----------------
__global__ void heads(const float* __restrict__ f, const float* __restrict__ rw,
                      const float* __restrict__ rb, const float* __restrict__ cw,
                      const float* __restrict__ cb, float* __restrict__ out)
{
  int b = blockIdx.x * 4 + (threadIdx.x >> 6);
  int lane = threadIdx.x & 63;
  float pr = 0.f, pc = 0.f;
  for (int k = lane; k < 1024; k += 64) {
    float x = f[(size_t)b * 1024 + k];
    pr += x * rw[k]; pc += x * cw[k];
  }
  for (int m = 32; m; m >>= 1) { pr += __shfl_xor(pr, m); pc += __shfl_xor(pc, m); }
  if (lane == 0) {
    out[b] = pr + rb[0];
    out[100 + b] = sigm(pc + cb[0]);
  }
}

// ============================================================================
extern "C" void kernel_launch(void* const* d_in, const int* in_sizes, int n_in,
                              void* d_out, int out_size, void* d_ws, size_t ws_size,
                              hipStream_t stream)
{
  const float* x     = (const float*)d_in[0];
  const float* Wih   = (const float*)d_in[1];
  const float* Whh   = (const float*)d_in[2];
  const float* bih   = (const float*)d_in[3];
  const float* bhh   = (const float*)d_in[4];
  const float* encW  = (const float*)d_in[5];
  const float* encb  = (const float*)d_in[6];
  const float* poolW = (const float*)d_in[7];
  const float* poolb = (const float*)d_in[8];
  const float* innW  = (const float*)d_in[9];
  const float* innas = (const float*)d_in[10];
  const float* innad = (const float*)d_in[11];
  const float* innb  = (const float*)d_in[12];
  const float* catW  = (const float*)d_in[13];
  const float* catas = (const float*)d_in[14];
  const float* catad = (const float*)d_in[15];
  const float* catb  = (const float*)d_in[16];
  const float* fusW  = (const float*)d_in[17];
  const float* fusb  = (const float*)d_in[18];
  const float* regW  = (const float*)d_in[19];
  const float* regb  = (const float*)d_in[20];
  const float* clsW  = (const float*)d_in[21];
  const float* clsb  = (const float*)d_in[22];
  float* out = (float*)d_out;
  char* ws = (char*)d_ws;

  unsigned short* xbf  = (unsigned short*)(ws + OF_XBF);
  unsigned short* hist = (unsigned short*)(ws + OF_HIST);
  int*            flg  = (int*)(ws + OF_FLAGS);
  unsigned short* ewbf = (unsigned short*)(ws + OF_ENCW);
  float* v    = (float*)(ws + OF_V);
  float* hin  = (float*)(ws + OF_HIN);
  float* iemb = (float*)(ws + OF_IEMB);
  float* catv = (float*)(ws + OF_CATV);
  float* cath = (float*)(ws + OF_CATH);
  float* cato = (float*)(ws + OF_CATO);
  float* fbuf = (float*)(ws + OF_FBUF);
  float* fout = (float*)(ws + OF_FOUT);

  (void)hipFuncSetAttribute((const void*)gru_recur, hipFuncAttributeMaxDynamicSharedMemorySize, GRU_LDS);
  (void)hipFuncSetAttribute((const void*)att_pool,  hipFuncAttributeMaxDynamicSharedMemorySize, ATT_LDS);

  // h(0) = 0 (slot 0) and flag reset — stream-ordered, visible at kernel dispatch
  (void)hipMemsetAsync(hist, 0, 204800, stream);
  (void)hipMemsetAsync(flg, 0, 65536, stream);

  f2bf_kernel<<<12800, 256, 0, stream>>>(x, xbf, 13107200 / 4);
  f2bf_kernel<<<256,   256, 0, stream>>>(encW, ewbf, 262144 / 4);

  gru_recur<<<64, 320, GRU_LDS, stream>>>(xbf, Whh, Wih, bih, bhh, hist, flg);
  att_pool<<<1600, 512, ATT_LDS, stream>>>(hist, ewbf, encb, v);

  gemm_bt<<<dim3(16, 7), 256, 0, stream>>>(v, innW, hin, 100, 1024, 1024, nullptr, 0);
  gat_att<20><<<5, 256, 0, stream>>>(hin, innas, innad, innb, iemb);
  pool_att<<<20, 256, 0, stream>>>(v, poolW, poolb, catv);
  gemm_bt<<<dim3(16, 1), 256, 0, stream>>>(catv, catW, cath, 5, 1024, 1024, nullptr, 0);
  gat_att<5><<<1, 256, 0, stream>>>(cath, catas, catad, catb, cato);
  concat_kernel<<<1200, 256, 0, stream>>>(v, cato, iemb, fbuf);
  gemm_bt<<<dim3(16, 7), 256, 0, stream>>>(fbuf, fusW, fout, 100, 1024, 3072, fusb, 1);
  heads<<<25, 256, 0, stream>>>(fout, regW, regb, clsW, clsb, out);

  (void)in_sizes; (void)n_in; (void)out_size; (void)ws_size;
}

// Round 2
// 12197.111 us; speedup vs baseline: 1.0007x; 1.0007x over previous
//
#include <hip/hip_runtime.h>
#include <hip/hip_bf16.h>

// ============================================================================
// CategoricalGraphAtt on MI355X.
// R7 = R6 with the register-spill bug fixed: __launch_bounds__(320,2) capped
// the per-wave register budget at 256 (VGPR_Count showed 128+128AGPR = cap),
// forcing ~50 regs of Breg/acc to spill to scratch inside the 512-step t-loop
// (21.6us/step, MfmaUtil 1.6%). Only one WG/CU fits anyway (137KB LDS), so
// drop the min-waves clause and restore the 512-reg budget.
// Structure (from R6): one batch-group, M=100 rows/WG, 64 WGs (1 per slice).
// hist layout [t][slice 64][row 100][j 16]; fp32 h-state in registers.
// ============================================================================

typedef __bf16 bf16x8 __attribute__((ext_vector_type(8)));
typedef float  floatx4 __attribute__((ext_vector_type(4)));
typedef int    intx4  __attribute__((ext_vector_type(4)));

struct US8 { unsigned short u[8]; };

__device__ __forceinline__ unsigned short f2bf(float f) {
  unsigned u = __builtin_bit_cast(unsigned, f);
  u += 0x7fffu + ((u >> 16) & 1u);           // RNE
  return (unsigned short)(u >> 16);
}
__device__ __forceinline__ float bf2f(unsigned short h) {
  return __builtin_bit_cast(float, ((unsigned)h) << 16);
}
__device__ __forceinline__ float sigm(float x) { return 1.f / (1.f + __expf(-x)); }

// raw barrier: LDS-only ordering (no vmcnt drain)
__device__ __forceinline__ void bar_lds() {
  asm volatile("s_waitcnt lgkmcnt(0)" ::: "memory");
  __builtin_amdgcn_s_barrier();
  asm volatile("" ::: "memory");
}

// ---------------- workspace layout (bytes) ----------------
static const size_t OF_XBF   = 0;                 // bf16 x [100][512][256]   26,214,400
static const size_t OF_HIST  = 26214400;          // bf16 h_hist [513][64 s][100 r][16 j] 105,062,400
static const size_t OF_ENCW  = 131277824;         // bf16 enc_att_W [512][512] 524,288
static const size_t OF_V     = 131802112;         // f32 v [100][1024]
static const size_t OF_HIN   = 132211712;         // f32 inner-GAT h
static const size_t OF_IEMB  = 132621312;         // f32 inner_emb
static const size_t OF_CATV  = 133030912;         // f32 cat_vec (pooled) [5][1024]
static const size_t OF_CATH  = 133051392;         // f32 cat-GAT h
static const size_t OF_CATO  = 133071872;         // f32 cat GAT out
static const size_t OF_FBUF  = 133092352;         // f32 fusion input [100][3072]
static const size_t OF_FOUT  = 134321152;         // f32 fusion output [100][1024]
static const size_t OF_FLAGS = 134730752;         // int flags[64 cwg][4 wave][16] = 16,384 (65,536 reserved)

// ---------------- fp32 -> bf16 convert ----------------
__global__ void f2bf_kernel(const float* __restrict__ src, unsigned short* __restrict__ dst, int n4) {
  int i = blockIdx.x * 256 + threadIdx.x;
  if (i < n4) {
    float4 v = ((const float4*)src)[i];
    ushort4 o;
    o.x = f2bf(v.x); o.y = f2bf(v.y); o.z = f2bf(v.z); o.w = f2bf(v.w);
    ((ushort4*)dst)[i] = o;
  }
}

// ---------------- GRU epilogue: one (col l, row-quad q) unit ----------------
// ghp blocks: [(w*7+mt)*3+gg][16 col * 20 stride], gates gg: 0=r 1=z 2=hn (w<4) / xn (w=4)
__device__ __forceinline__ void gru_epi(int u, floatx4& h4, const float* ghp,
                                        const float* biasl, unsigned short* hb16) {
  int l = u & 15, q = u >> 4;              // l: hidden col, q: row-quad (rows q*4..q*4+3)
  int mt2 = q >> 2, rr0 = (q & 3) * 4;
  const float* g0 = ghp + (size_t)(mt2 * 3) * 320 + l * 20 + rr0;
  floatx4 ghr  = *(const floatx4*)(g0);
  floatx4 ghz  = *(const floatx4*)(g0 + 320);
  floatx4 ghnh = *(const floatx4*)(g0 + 640);
  #pragma unroll
  for (int ww = 1; ww < 4; ww++) {
    const float* gq = g0 + ww * (21 * 320);
    ghr  += *(const floatx4*)(gq);
    ghz  += *(const floatx4*)(gq + 320);
    ghnh += *(const floatx4*)(gq + 640);
  }
  const float* gx = g0 + 4 * (21 * 320);   // wave-4 (x-part) block
  ghr += *(const floatx4*)(gx);
  ghz += *(const floatx4*)(gx + 320);
  floatx4 ghnx = *(const floatx4*)(gx + 640);
  float br = biasl[l], bz = biasl[16 + l], bnh = biasl[32 + l], bnx = biasl[48 + l];
  #pragma unroll
  for (int j = 0; j < 4; j++) {
    float r = sigm(ghr[j] + br);
    float z = sigm(ghz[j] + bz);
    float nv = ghnx[j] + bnx + r * (ghnh[j] + bnh);
    nv = fminf(fmaxf(nv, -15.f), 15.f);
    float e2 = __expf(-2.f * nv);
    float n = (1.f - e2) / (1.f + e2);
    float hn = (1.f - z) * n + z * h4[j];
    h4[j] = hn;
    hb16[(q * 4 + j) * 16 + l] = f2bf(hn);
  }
}

// ---------------- persistent GRU recurrence ----------------
// grid 64 = 64 slices (16 j each), M = all 100 rows. block 320 (5 waves).
// waves 0-3: k-steps 8w..8w+8 of h-part (K=1024); wave 4: x-part (K=256) +
// the whole store/flag tail.
// hist layout per step: [slice s(64)][row(100)][16 j] bf16 (1600 shorts/slice).
// LDS: ghp [105 blk][16 col * 20] f32 @0 (134,400; overlays Bw 122,880 init
//      scratch) | hb16 [100][16] bf16 @134,400 | bias [4][16] @137,600.
#define GRU_LDS 137856
__global__ void __launch_bounds__(320) gru_recur(
    const unsigned short* __restrict__ xbf,
    const float* __restrict__ Whh, const float* __restrict__ Wih,
    const float* __restrict__ bih, const float* __restrict__ bhh,
    unsigned short* hist, int* flags)
{
  extern __shared__ char smem[];
  float* ghp  = (float*)smem;                        // [105][320] partials (post-init)
  unsigned short* hb16 = (unsigned short*)(smem + 134400);  // [100][16] staged h'
  float* biasl = (float*)(smem + 137600);            // [4][16]: r,z,hn,xn
  unsigned short* Bw  = (unsigned short*)smem;       // init-only gather scratch

  const int tid  = threadIdx.x;
  const int lane = tid & 63;
  const int w    = tid >> 6;       // 0..4
  const int s    = blockIdx.x;     // slice 0..63
  const int myq  = s >> 4;         // producer quarter

  // ---- gather B (Whh/Wih rows for this slice) into LDS in frag order ----
  for (int o = tid; o < 7680; o += 320) {
    int kk, ln; const float* sp; unsigned short* dst;
    if (o < 5120) {
      int q = o >= 2560; int rem = o - q * 2560;
      kk = rem >> 6; ln = rem & 63;
      int l = ln & 15, ksub = ln >> 4, j = s * 16 + l;
      int k = kk * 32 + ksub * 8;
      sp = (k < 1024) ? (Whh + (size_t)(q * 1024 + j) * 1024 + k)
                      : (Wih + (size_t)(q * 1024 + j) * 256 + (k - 1024));
      dst = Bw + ((size_t)((q * 40 + kk) * 64 + ln)) * 8;
    } else if (o < 7168) {
      int o2 = o - 5120; kk = o2 >> 6; ln = o2 & 63;
      int l = ln & 15, ksub = ln >> 4, j = s * 16 + l;
      sp = Whh + (size_t)(2048 + j) * 1024 + kk * 32 + ksub * 8;
      dst = Bw + (size_t)(5120 + kk * 64 + ln) * 8;
    } else {
      int o3 = o - 7168; kk = o3 >> 6; ln = o3 & 63;
      int l = ln & 15, ksub = ln >> 4, j = s * 16 + l;
      sp = Wih + (size_t)(2048 + j) * 256 + kk * 32 + ksub * 8;
      dst = Bw + (size_t)(7168 + kk * 64 + ln) * 8;
    }
    float4 f0 = *(const float4*)sp;
    float4 f1 = *(const float4*)(sp + 4);
    dst[0] = f2bf(f0.x); dst[1] = f2bf(f0.y); dst[2] = f2bf(f0.z); dst[3] = f2bf(f0.w);
    dst[4] = f2bf(f1.x); dst[5] = f2bf(f1.y); dst[6] = f2bf(f1.z); dst[7] = f2bf(f1.w);
  }
  if (tid < 16) {
    int j = s * 16 + tid;
    biasl[tid]      = bih[j]        + bhh[j];
    biasl[16 + tid] = bih[1024 + j] + bhh[1024 + j];
    biasl[32 + tid] = bhh[2048 + j];
    biasl[48 + tid] = bih[2048 + j];
  }
  __syncthreads();

  // ---- hoist B fragments (persist across all 512 steps) ----
  bf16x8 Breg[24];
  #pragma unroll
  for (int lk = 0; lk < 8; lk++) {
    int kk = w * 8 + lk;
    Breg[lk * 3 + 0] = __builtin_bit_cast(bf16x8, *(const intx4*)(Bw + (size_t)((kk)      * 64 + lane) * 8));
    Breg[lk * 3 + 1] = __builtin_bit_cast(bf16x8, *(const intx4*)(Bw + (size_t)((40 + kk) * 64 + lane) * 8));
    const unsigned short* np = (w < 4)
        ? (Bw + (size_t)(5120 + kk * 64 + lane) * 8)
        : (Bw + (size_t)(7168 + (kk - 32) * 64 + lane) * 8);
    Breg[lk * 3 + 2] = __builtin_bit_cast(bf16x8, *(const intx4*)np);
  }
  __syncthreads();   // ghp overlays Bw: no partial writes before all hoists done

  // A-operand addressing.
  // h (slice-major): slice = 2*kk + (lane>>5); elem = slice*1600 + row*16 + ((lane>>4)&1)*8
  // x (row-major): xbf + row*512*256 + t*256 + (kk-32)*32 + (lane>>4)*8
  const int kf_h = ((lane >> 4) & 1) * 8;
  const int kf_x = (lane >> 4) * 8;
  int baseA[7], rowx[7];
  #pragma unroll
  for (int mt = 0; mt < 7; mt++) {
    int m = mt * 16 + (lane & 15);
    int bb = (m < 100) ? m : 99;           // clamp pad rows
    baseA[mt] = (lane >> 5) * 1600 + bb * 16 + kf_h;
    rowx[mt]  = bb * 131072;               // 512*256 shorts per row
  }

  const int* pollline = flags + (s * 4 + w) * 16;      // private per (WG, wave)
  floatx4 h4a = {0.f, 0.f, 0.f, 0.f};                  // fp32 h state in regs
  floatx4 h4b = {0.f, 0.f, 0.f, 0.f};                  // (second unit, tid<80)

  for (int t = 0; t < 512; t++) {
    // ---- wait for this wave's k-quarter producers (private line, no sleep) ----
    if (w < 4) {
      for (;;) {
        int f = __hip_atomic_load(pollline + (lane & 15), __ATOMIC_RELAXED, __HIP_MEMORY_SCOPE_AGENT);
        if (__all(f >= t)) break;
      }
      asm volatile("" ::: "memory");   // no hoisting of h loads above the spin
    }

    const unsigned short* hrow = hist + (size_t)t * 102400;
    const unsigned short* xrow = xbf + t * 256;
    floatx4 acc[7][3];
    #pragma unroll
    for (int mt = 0; mt < 7; mt++)
      #pragma unroll
      for (int gg = 0; gg < 3; gg++) acc[mt][gg] = floatx4{0.f, 0.f, 0.f, 0.f};

    #pragma unroll
    for (int lk = 0; lk < 8; lk++) {
      int kk = w * 8 + lk;
      #pragma unroll
      for (int mt = 0; mt < 7; mt++) {
        const unsigned short* ap = (w < 4)
            ? (hrow + baseA[mt] + kk * 3200)
            : (xrow + rowx[mt] + (kk - 32) * 32 + kf_x);
        bf16x8 a = __builtin_bit_cast(bf16x8, *(const intx4*)ap);
        acc[mt][0] = __builtin_amdgcn_mfma_f32_16x16x32_bf16(a, Breg[lk * 3 + 0], acc[mt][0], 0, 0, 0);
        acc[mt][1] = __builtin_amdgcn_mfma_f32_16x16x32_bf16(a, Breg[lk * 3 + 1], acc[mt][1], 0, 0, 0);
        acc[mt][2] = __builtin_amdgcn_mfma_f32_16x16x32_bf16(a, Breg[lk * 3 + 2], acc[mt][2], 0, 0, 0);
      }
    }

    // partials -> LDS: [block][col l * 20][rows at q*4] (float4 per quad)
    {
      int pb = (lane & 15) * 20 + (lane >> 4) * 4;
      #pragma unroll
      for (int mt = 0; mt < 7; mt++)
        #pragma unroll
        for (int gg = 0; gg < 3; gg++)
          *(floatx4*)(ghp + (size_t)((w * 7 + mt) * 3 + gg) * 320 + pb) = acc[mt][gg];
    }
    bar_lds();   // (1) partials visible

    // ---- epilogue: 400 (col, row-quad) units over 320 threads ----
    gru_epi(tid, h4a, ghp, biasl, hb16);
    if (tid < 80) gru_epi(tid + 320, h4b, ghp, biasl, hb16);

    bar_lds();   // (2) hb16 visible to wave 4; ghp free for next MFMA round

    // ---- wave 4: contiguous 16B write-through stores + ack + flag fan-out ----
    if (w == 4) {
      unsigned long long hbase = (unsigned long long)(hist + (size_t)(t + 1) * 102400
                                                      + (size_t)s * 1600);
      #pragma unroll
      for (int i = 0; i < 3; i++) {
        int c = lane + 64 * i;             // 200 chunks of 16B (100 rows x 2 halves)
        intx4 d = *(const intx4*)(hb16 + c * 8);
        asm volatile("global_store_dwordx4 %0, %1, off sc0 sc1"
                     :: "v"(hbase + (unsigned long long)c * 16), "v"(d) : "memory");
      }
      if (lane < 8) {
        int c = 192 + lane;
        intx4 d = *(const intx4*)(hb16 + c * 8);
        asm volatile("global_store_dwordx4 %0, %1, off sc0 sc1"
                     :: "v"(hbase + (unsigned long long)c * 16), "v"(d) : "memory");
      }
      if (t < 511) {
        asm volatile("s_waitcnt vmcnt(0)" ::: "memory");   // h' at MALL before flags
        __hip_atomic_store(flags + (lane * 4 + myq) * 16 + (s & 15), t + 1,
                           __ATOMIC_RELAXED, __HIP_MEMORY_SCOPE_AGENT);
      }
    }
    // waves 0-3 fall through to the next poll immediately.
  }
}

// ---------------- fused time attention ----------------
// grid 1600 (one 64-col block of n'=(b*1024+d)), block 512 (8 waves).
#define ATT_LDS 68096
__global__ void __launch_bounds__(512) att_pool(
    const unsigned short* __restrict__ hist,   // slots 1..512, slice-major
    const unsigned short* __restrict__ encw,   // bf16 [512][512]
    const float* __restrict__ encb,
    float* __restrict__ vout)
{
  extern __shared__ char smem[];
  unsigned short* Bs = (unsigned short*)smem;          // [16ks][4nt][64lane][8]
  float* red  = (float*)(smem + 65536);                // [8][64]
  float* cmax = (float*)(smem + 65536 + 2048);
  float* csum = (float*)(smem + 65536 + 2048 + 256);

  const int tid = threadIdx.x, w = tid >> 6, lane = tid & 63;
  const int q = lane >> 4, col = lane & 15;
  const int n0 = blockIdx.x * 64;
  const int bA = n0 >> 10, d0 = n0 & 1023;

  // stage hs tile (slice-major gather, transposed scatter into frag layout)
  for (int ii = 0; ii < 8; ii++) {
    int c = tid + 512 * ii;
    int t = c >> 3, dd = c & 7;
    int sA = (d0 >> 4) + (dd >> 1), hsA = dd & 1;
    intx4 li = *(const intx4*)(hist + (size_t)(t + 1) * 102400
                             + (size_t)(sA * 1600 + bA * 16 + hsA * 8));
    US8 u8 = __builtin_bit_cast(US8, li);
    int kstep = t >> 5, ksub = (t >> 3) & 3, i = t & 7;
    int ntile = dd >> 1, nc0 = (dd & 1) * 8;
    unsigned short* dst = Bs + ((size_t)((kstep * 4 + ntile) * 64 + ksub * 16 + nc0)) * 8 + i;
    #pragma unroll
    for (int jj = 0; jj < 8; jj++) dst[jj * 8] = u8.u[jj];
  }
  __syncthreads();

  floatx4 acc[4][4];
  #pragma unroll
  for (int mi = 0; mi < 4; mi++)
    #pragma unroll
    for (int ni = 0; ni < 4; ni++) acc[mi][ni] = floatx4{0.f, 0.f, 0.f, 0.f};

  #pragma unroll 2
  for (int kk = 0; kk < 16; kk++) {
    int tch = kk * 32 + q * 8;
    bf16x8 af[4];
    #pragma unroll
    for (int mi = 0; mi < 4; mi++) {
      int u = (w * 4 + mi) * 16 + col;
      af[mi] = __builtin_bit_cast(bf16x8, *(const intx4*)(encw + (size_t)u * 512 + tch));
    }
    #pragma unroll
    for (int ni = 0; ni < 4; ni++) {
      bf16x8 bf = __builtin_bit_cast(bf16x8, *(const intx4*)(Bs + (size_t)((kk * 4 + ni) * 64 + lane) * 8));
      #pragma unroll
      for (int mi = 0; mi < 4; mi++)
        acc[mi][ni] = __builtin_amdgcn_mfma_f32_16x16x32_bf16(af[mi], bf, acc[mi][ni], 0, 0, 0);
    }
  }

  // + row bias
  #pragma unroll
  for (int mi = 0; mi < 4; mi++) {
    int ub = (w * 4 + mi) * 16 + q * 4;
    float b0 = encb[ub], b1 = encb[ub + 1], b2 = encb[ub + 2], b3 = encb[ub + 3];
    #pragma unroll
    for (int ni = 0; ni < 4; ni++) {
      acc[mi][ni][0] += b0; acc[mi][ni][1] += b1; acc[mi][ni][2] += b2; acc[mi][ni][3] += b3;
    }
  }
  // column max
  #pragma unroll
  for (int ni = 0; ni < 4; ni++) {
    float m = -1e30f;
    #pragma unroll
    for (int mi = 0; mi < 4; mi++)
      #pragma unroll
      for (int r = 0; r < 4; r++) m = fmaxf(m, acc[mi][ni][r]);
    m = fmaxf(m, __shfl_xor(m, 16)); m = fmaxf(m, __shfl_xor(m, 32));
    red[w * 64 + ni * 16 + col] = m;
  }
  __syncthreads();
  if (tid < 64) {
    float m = red[tid];
    for (int w2 = 1; w2 < 8; w2++) m = fmaxf(m, red[w2 * 64 + tid]);
    cmax[tid] = m;
  }
  __syncthreads();
  // exp + column sum
  #pragma unroll
  for (int ni = 0; ni < 4; ni++) {
    float cm = cmax[ni * 16 + col];
    float sum = 0.f;
    #pragma unroll
    for (int mi = 0; mi < 4; mi++)
      #pragma unroll
      for (int r = 0; r < 4; r++) {
        float e = __expf(acc[mi][ni][r] - cm);
        acc[mi][ni][r] = e; sum += e;
      }
    sum += __shfl_xor(sum, 16); sum += __shfl_xor(sum, 32);
    red[w * 64 + ni * 16 + col] = sum;
  }
  __syncthreads();
  if (tid < 64) {
    float sm = 0.f;
    for (int w2 = 0; w2 < 8; w2++) sm += red[w2 * 64 + tid];
    csum[tid] = sm;
  }
  __syncthreads();
  // weighted sum of hs
  #pragma unroll
  for (int ni = 0; ni < 4; ni++) {
    float p = 0.f;
    #pragma unroll
    for (int mi = 0; mi < 4; mi++) {
      int u0 = (w * 4 + mi) * 16 + q * 4;
      int ks = u0 >> 5, ksb = (u0 >> 3) & 3, i0 = u0 & 7;
      const unsigned short* hp = Bs + (size_t)((ks * 4 + ni) * 64 + ksb * 16 + col) * 8 + i0;
      p += acc[mi][ni][0] * bf2f(hp[0]) + acc[mi][ni][1] * bf2f(hp[1])
         + acc[mi][ni][2] * bf2f(hp[2]) + acc[mi][ni][3] * bf2f(hp[3]);
    }
    p += __shfl_xor(p, 16); p += __shfl_xor(p, 32);
    red[w * 64 + ni * 16 + col] = p;
  }
  __syncthreads();
  if (tid < 64) {
    float p = 0.f;
    for (int w2 = 0; w2 < 8; w2++) p += red[w2 * 64 + tid];
    vout[n0 + tid] = p / csum[tid];
  }
}

// ---------------- small fp32 GEMM: C(M,N) = A(M,K) @ B(N,K)^T [+bias][+relu] ----------------
__global__ void gemm_bt(const float* __restrict__ A, const float* __restrict__ B,
                        float* __restrict__ C, int M, int N, int K,
                        const float* __restrict__ bias, int relu)
{
  __shared__ float Al[16][33];
  __shared__ float Bl[64][33];
  int tx = threadIdx.x;
  int nb = blockIdx.x, mb = blockIdx.y;
  int n = nb * 64 + (tx & 63);
  int mq = tx >> 6;
  float acc[4] = {0.f, 0.f, 0.f, 0.f};
  for (int k0 = 0; k0 < K; k0 += 32) {
    for (int e = tx; e < 512; e += 256) {
      int r = e >> 5, c = e & 31; int m = mb * 16 + r;
      Al[r][c] = (m < M) ? A[(size_t)m * K + k0 + c] : 0.f;
    }
    for (int e = tx; e < 2048; e += 256) {
      int r = e >> 5, c = e & 31;
      Bl[r][c] = B[(size_t)(nb * 64 + r) * K + k0 + c];
    }
    __syncthreads();
    int nn = tx & 63;
    #pragma unroll 8
    for (int c = 0; c < 32; c++) {
      float bv = Bl[nn][c];
      #pragma unroll
      for (int i = 0; i < 4; i++) acc[i] += Al[mq * 4 + i][c] * bv;
    }
    __syncthreads();
  }
  #pragma unroll
  for (int i = 0; i < 4; i++) {
    int m = mb * 16 + mq * 4 + i;
    if (m < M && n < N) {
      float r = acc[i] + (bias ? bias[n] : 0.f);
      if (relu) r = fmaxf(r, 0.f);
      C[(size_t)m * N + n] = r;
    }
  }
}

// ---------------- GAT attention (complete graph + self loops within each block of NN nodes) ----------------
template <int NN>
__global__ void gat_att(const float* __restrict__ h, const float* __restrict__ asrc,
                        const float* __restrict__ adst, const float* __restrict__ bias,
                        float* __restrict__ out)
{
  __shared__ float asd[2][NN];
  __shared__ float P[NN][NN];
  int c = blockIdx.x, tx = threadIdx.x;
  int wid = tx >> 6, lane = tx & 63;
  for (int idx = wid; idx < 2 * NN; idx += 4) {
    int which = idx >= NN; int j = which ? idx - NN : idx;
    const float* av = which ? adst : asrc;
    float p = 0.f;
    for (int k = lane; k < 1024; k += 64) p += h[(size_t)(c * NN + j) * 1024 + k] * av[k];
    for (int m = 32; m; m >>= 1) p += __shfl_xor(p, m);
    if (lane == 0) asd[which][j] = p;
  }
  __syncthreads();
  if (tx < NN) {
    int i = tx; float mx = -1e30f; float e[NN];
    #pragma unroll
    for (int j = 0; j < NN; j++) {
      float x = asd[0][j] + asd[1][i];
      x = (x < 0.f) ? 0.2f * x : x;
      e[j] = x; mx = fmaxf(mx, x);
    }
    float s = 0.f;
    #pragma unroll
    for (int j = 0; j < NN; j++) { e[j] = __expf(e[j] - mx); s += e[j]; }
    #pragma unroll
    for (int j = 0; j < NN; j++) P[i][j] = e[j] / s;
  }
  __syncthreads();
  for (int ee = tx; ee < NN * 1024; ee += 256) {
    int i = ee >> 10, d = ee & 1023;
    float s = 0.f;
    #pragma unroll
    for (int j = 0; j < NN; j++) s += P[i][j] * h[(size_t)(c * NN + j) * 1024 + d];
    out[(size_t)(c * NN + i) * 1024 + d] = s + bias[d];
  }
}

// ---------------- stock->category pooling attention ----------------
__global__ void pool_att(const float* __restrict__ v, const float* __restrict__ pW,
                         const float* __restrict__ pb, float* __restrict__ catv)
{
  __shared__ float W[400]; __shared__ float bsh[20];
  int tx = threadIdx.x;
  for (int i = tx; i < 400; i += 256) W[i] = pW[i];
  if (tx < 20) bsh[tx] = pb[tx];
  __syncthreads();
  int gid = blockIdx.x * 256 + tx;
  int c = gid >> 10, d = gid & 1023;
  float vals[20];
  #pragma unroll
  for (int t = 0; t < 20; t++) vals[t] = v[(size_t)(c * 20 + t) * 1024 + d];
  float wv[20]; float mx = -1e30f;
  #pragma unroll
  for (int u = 0; u < 20; u++) {
    float s = bsh[u];
    #pragma unroll
    for (int t = 0; t < 20; t++) s += vals[t] * W[u * 20 + t];
    wv[u] = s; mx = fmaxf(mx, s);
  }
  float sum = 0.f, out = 0.f;
  #pragma unroll
  for (int u = 0; u < 20; u++) { float e = __expf(wv[u] - mx); sum += e; out += e * vals[u]; }
  catv[gid] = out / sum;
}

// ---------------- fusion concat ----------------
__global__ void concat_kernel(const float* __restrict__ v, const float* __restrict__ cato,
                              const float* __restrict__ iemb, float* __restrict__ F)
{
  int gid = blockIdx.x * 256 + threadIdx.x;
  if (gid < 307200) {
    int i = gid / 3072;
    int k = gid - i * 3072;
    float r;
    if (k < 1024)       r = v[(size_t)i * 1024 + k];
    else if (k < 2048)  r = cato[(size_t)(i / 20) * 1024 + (k - 1024)];
    else                r = iemb[(size_t)i * 1024 + (k - 2048)];
    F[gid] = r;
  }
}

// ---------------- output heads ----------------
__global__ void heads(const float* __restrict__ f, const float* __restrict__ rw,
                      const float* __restrict__ rb, const float* __restrict__ cw,
                      const float* __restrict__ cb, float* __restrict__ out)
{
  int b = blockIdx.x * 4 + (threadIdx.x >> 6);
  int lane = threadIdx.x & 63;
  float pr = 0.f, pc = 0.f;
  for (int k = lane; k < 1024; k += 64) {
    float x = f[(size_t)b * 1024 + k];
    pr += x * rw[k]; pc += x * cw[k];
  }
  for (int m = 32; m; m >>= 1) { pr += __shfl_xor(pr, m); pc += __shfl_xor(pc, m); }
  if (lane == 0) {
    out[b] = pr + rb[0];
    out[100 + b] = sigm(pc + cb[0]);
  }
}

// ============================================================================
extern "C" void kernel_launch(void* const* d_in, const int* in_sizes, int n_in,
                              void* d_out, int out_size, void* d_ws, size_t ws_size,
                              hipStream_t stream)
{
  const float* x     = (const float*)d_in[0];
  const float* Wih   = (const float*)d_in[1];
  const float* Whh   = (const float*)d_in[2];
  const float* bih   = (const float*)d_in[3];
  const float* bhh   = (const float*)d_in[4];
  const float* encW  = (const float*)d_in[5];
  const float* encb  = (const float*)d_in[6];
  const float* poolW = (const float*)d_in[7];
  const float* poolb = (const float*)d_in[8];
  const float* innW  = (const float*)d_in[9];
  const float* innas = (const float*)d_in[10];
  const float* innad = (const float*)d_in[11];
  const float* innb  = (const float*)d_in[12];
  const float* catW  = (const float*)d_in[13];
  const float* catas = (const float*)d_in[14];
  const float* catad = (const float*)d_in[15];
  const float* catb  = (const float*)d_in[16];
  const float* fusW  = (const float*)d_in[17];
  const float* fusb  = (const float*)d_in[18];
  const float* regW  = (const float*)d_in[19];
  const float* regb  = (const float*)d_in[20];
  const float* clsW  = (const float*)d_in[21];
  const float* clsb  = (const float*)d_in[22];
  float* out = (float*)d_out;
  char* ws = (char*)d_ws;

  unsigned short* xbf  = (unsigned short*)(ws + OF_XBF);
  unsigned short* hist = (unsigned short*)(ws + OF_HIST);
  int*            flg  = (int*)(ws + OF_FLAGS);
  unsigned short* ewbf = (unsigned short*)(ws + OF_ENCW);
  float* v    = (float*)(ws + OF_V);
  float* hin  = (float*)(ws + OF_HIN);
  float* iemb = (float*)(ws + OF_IEMB);
  float* catv = (float*)(ws + OF_CATV);
  float* cath = (float*)(ws + OF_CATH);
  float* cato = (float*)(ws + OF_CATO);
  float* fbuf = (float*)(ws + OF_FBUF);
  float* fout = (float*)(ws + OF_FOUT);

  (void)hipFuncSetAttribute((const void*)gru_recur, hipFuncAttributeMaxDynamicSharedMemorySize, GRU_LDS);
  (void)hipFuncSetAttribute((const void*)att_pool,  hipFuncAttributeMaxDynamicSharedMemorySize, ATT_LDS);

  // h(0) = 0 (slot 0) and flag reset — stream-ordered, visible at kernel dispatch
  (void)hipMemsetAsync(hist, 0, 204800, stream);
  (void)hipMemsetAsync(flg, 0, 65536, stream);

  f2bf_kernel<<<12800, 256, 0, stream>>>(x, xbf, 13107200 / 4);
  f2bf_kernel<<<256,   256, 0, stream>>>(encW, ewbf, 262144 / 4);

  gru_recur<<<64, 320, GRU_LDS, stream>>>(xbf, Whh, Wih, bih, bhh, hist, flg);
  att_pool<<<1600, 512, ATT_LDS, stream>>>(hist, ewbf, encb, v);

  gemm_bt<<<dim3(16, 7), 256, 0, stream>>>(v, innW, hin, 100, 1024, 1024, nullptr, 0);
  gat_att<20><<<5, 256, 0, stream>>>(hin, innas, innad, innb, iemb);
  pool_att<<<20, 256, 0, stream>>>(v, poolW, poolb, catv);
  gemm_bt<<<dim3(16, 1), 256, 0, stream>>>(catv, catW, cath, 5, 1024, 1024, nullptr, 0);
  gat_att<5><<<1, 256, 0, stream>>>(cath, catas, catad, catb, cato);
  concat_kernel<<<1200, 256, 0, stream>>>(v, cato, iemb, fbuf);
  gemm_bt<<<dim3(16, 7), 256, 0, stream>>>(fbuf, fusW, fout, 100, 1024, 3072, fusb, 1);
  heads<<<25, 256, 0, stream>>>(fout, regW, regb, clsW, clsb, out);

  (void)in_sizes; (void)n_in; (void)out_size; (void)ws_size;
}

// Round 3
// 11612.572 us; speedup vs baseline: 1.0511x; 1.0503x over previous
//
#include <hip/hip_runtime.h>
#include <hip/hip_bf16.h>

// ============================================================================
// CategoricalGraphAtt on MI355X.
// R8: fix the R6/R7 register-spill structurally. A 5-wave (320t) WG physically
// caps at 256 regs/wave (one SIMD hosts 2 waves; file = 512/SIMD), so Breg+acc
// spilled to scratch inside the t-loop (L2-resident, invisible in FETCH, 3.5x
// slower). New shape: 4 waves (256t), 1 wave/SIMD, amdgpu_waves_per_eu(1) ->
// 512-reg budget. Each wave: 8 h k-steps (its K-quarter) + 2 x k-steps, with
// separate accx for gate-n's x-part. x-frags prefetched before the poll.
// Stores: each wave writes its own 25 rows (sc0sc1) + vmcnt(0) + per-rowgroup
// flag; consumers poll 64 flag words (16 slices x 4 rowgroups) lane-parallel.
// hist layout [t][slice 64][row 100][j 16] (unchanged from R6/R7).
// ============================================================================

typedef __bf16 bf16x8 __attribute__((ext_vector_type(8)));
typedef float  floatx4 __attribute__((ext_vector_type(4)));
typedef int    intx4  __attribute__((ext_vector_type(4)));

struct US8 { unsigned short u[8]; };

__device__ __forceinline__ unsigned short f2bf(float f) {
  unsigned u = __builtin_bit_cast(unsigned, f);
  u += 0x7fffu + ((u >> 16) & 1u);           // RNE
  return (unsigned short)(u >> 16);
}
__device__ __forceinline__ float bf2f(unsigned short h) {
  return __builtin_bit_cast(float, ((unsigned)h) << 16);
}
__device__ __forceinline__ float sigm(float x) { return 1.f / (1.f + __expf(-x)); }

// raw barrier: LDS-only ordering (no vmcnt drain)
__device__ __forceinline__ void bar_lds() {
  asm volatile("s_waitcnt lgkmcnt(0)" ::: "memory");
  __builtin_amdgcn_s_barrier();
  asm volatile("" ::: "memory");
}

// ---------------- workspace layout (bytes) ----------------
static const size_t OF_XBF   = 0;                 // bf16 x [100][512][256]   26,214,400
static const size_t OF_HIST  = 26214400;          // bf16 h_hist [513][64 s][100 r][16 j] 105,062,400
static const size_t OF_ENCW  = 131277824;         // bf16 enc_att_W [512][512] 524,288
static const size_t OF_V     = 131802112;         // f32 v [100][1024]
static const size_t OF_HIN   = 132211712;         // f32 inner-GAT h
static const size_t OF_IEMB  = 132621312;         // f32 inner_emb
static const size_t OF_CATV  = 133030912;         // f32 cat_vec (pooled) [5][1024]
static const size_t OF_CATH  = 133051392;         // f32 cat-GAT h
static const size_t OF_CATO  = 133071872;         // f32 cat GAT out
static const size_t OF_FBUF  = 133092352;         // f32 fusion input [100][3072]
static const size_t OF_FOUT  = 134321152;         // f32 fusion output [100][1024]
static const size_t OF_FLAGS = 134730752;         // int flags[64 cwg][4 q][16 slice][4 rg] = 65,536

// ---------------- fp32 -> bf16 convert ----------------
__global__ void f2bf_kernel(const float* __restrict__ src, unsigned short* __restrict__ dst, int n4) {
  int i = blockIdx.x * 256 + threadIdx.x;
  if (i < n4) {
    float4 v = ((const float4*)src)[i];
    ushort4 o;
    o.x = f2bf(v.x); o.y = f2bf(v.y); o.z = f2bf(v.z); o.w = f2bf(v.w);
    ((ushort4*)dst)[i] = o;
  }
}

// ---------------- GRU epilogue: one (col l, row-quad q) unit ----------------
// ghp blocks: [(w*7+mt)*4+gg][16 col * 20 stride], gates gg: 0=r 1=z 2=hn 3=xn
__device__ __forceinline__ void gru_epi(int u, floatx4& h4, const float* ghp,
                                        const float* biasl, unsigned short* hb16) {
  int l = u & 15, q = u >> 4;              // l: hidden col, q: row-quad (rows q*4..q*4+3)
  int mt2 = q >> 2, rr0 = (q & 3) * 4;
  const float* g0 = ghp + (size_t)(mt2 * 4) * 320 + l * 20 + rr0;
  floatx4 ghr  = *(const floatx4*)(g0);
  floatx4 ghz  = *(const floatx4*)(g0 + 320);
  floatx4 ghnh = *(const floatx4*)(g0 + 640);
  floatx4 ghnx = *(const floatx4*)(g0 + 960);
  #pragma unroll
  for (int ww = 1; ww < 4; ww++) {
    const float* gq = g0 + ww * (28 * 320);
    ghr  += *(const floatx4*)(gq);
    ghz  += *(const floatx4*)(gq + 320);
    ghnh += *(const floatx4*)(gq + 640);
    ghnx += *(const floatx4*)(gq + 960);
  }
  float br = biasl[l], bz = biasl[16 + l], bnh = biasl[32 + l], bnx = biasl[48 + l];
  #pragma unroll
  for (int j = 0; j < 4; j++) {
    float r = sigm(ghr[j] + br);
    float z = sigm(ghz[j] + bz);
    float nv = ghnx[j] + bnx + r * (ghnh[j] + bnh);
    nv = fminf(fmaxf(nv, -15.f), 15.f);
    float e2 = __expf(-2.f * nv);
    float n = (1.f - e2) / (1.f + e2);
    float hn = (1.f - z) * n + z * h4[j];
    h4[j] = hn;
    hb16[(q * 4 + j) * 16 + l] = f2bf(hn);
  }
}

// ---------------- persistent GRU recurrence ----------------
// grid 64 = 64 slices (16 j each), M = all 100 rows. block 256 (4 waves).
// wave w: h k-steps kk=8w..8w+8 (K=1024 total) + x k-steps glk=32+2w..32+2w+2
// (K=256 total), separate accx for gate-n x-part. Each wave stores rows
// [25w,25w+25) + vmcnt(0) + per-rowgroup flag fan-out (64 consumers).
// LDS: ghp [112 blk][16 col * 20] f32 @0 (143,360; overlays Bw 122,880 init
//      scratch) | hb16 [100][16] bf16 @143,360 | bias [4][16] @146,560.
#define GRU_LDS 146816
__global__ void __launch_bounds__(256) __attribute__((amdgpu_waves_per_eu(1))) gru_recur(
    const unsigned short* __restrict__ xbf,
    const float* __restrict__ Whh, const float* __restrict__ Wih,
    const float* __restrict__ bih, const float* __restrict__ bhh,
    unsigned short* hist, int* flags)
{
  extern __shared__ char smem[];
  float* ghp  = (float*)smem;                        // [112][320] partials (post-init)
  unsigned short* hb16 = (unsigned short*)(smem + 143360);  // [100][16] staged h'
  float* biasl = (float*)(smem + 146560);            // [4][16]: r,z,hn,xn
  unsigned short* Bw  = (unsigned short*)smem;       // init-only gather scratch

  const int tid  = threadIdx.x;
  const int lane = tid & 63;
  const int w    = tid >> 6;       // 0..3
  const int s    = blockIdx.x;     // slice 0..63
  const int myq  = s >> 4;         // producer quarter

  // ---- gather B (Whh/Wih rows for this slice) into LDS in frag order ----
  // Bw layout: [gate gg(3)][glk(40)][64 lane][8]; glk<32 = h (k=glk*32),
  // glk>=32 = x (kx=(glk-32)*32).
  for (int o = tid; o < 7680; o += 256) {
    int gg = o / 2560;
    int rem = o - gg * 2560;
    int glk = rem >> 6, ln = rem & 63;
    int l = ln & 15, ksub = ln >> 4, j = s * 16 + l;
    const float* sp = (glk < 32)
        ? (Whh + (size_t)(gg * 1024 + j) * 1024 + glk * 32 + ksub * 8)
        : (Wih + (size_t)(gg * 1024 + j) * 256 + (glk - 32) * 32 + ksub * 8);
    unsigned short* dst = Bw + ((size_t)((gg * 40 + glk) * 64 + ln)) * 8;
    float4 f0 = *(const float4*)sp;
    float4 f1 = *(const float4*)(sp + 4);
    dst[0] = f2bf(f0.x); dst[1] = f2bf(f0.y); dst[2] = f2bf(f0.z); dst[3] = f2bf(f0.w);
    dst[4] = f2bf(f1.x); dst[5] = f2bf(f1.y); dst[6] = f2bf(f1.z); dst[7] = f2bf(f1.w);
  }
  if (tid < 16) {
    int j = s * 16 + tid;
    biasl[tid]      = bih[j]        + bhh[j];
    biasl[16 + tid] = bih[1024 + j] + bhh[1024 + j];
    biasl[32 + tid] = bhh[2048 + j];
    biasl[48 + tid] = bih[2048 + j];
  }
  __syncthreads();

  // ---- hoist B fragments (persist across all 512 steps) ----
  // llk 0..7 -> h k-step glk = w*8+llk; llk 8..9 -> x k-step glk = 32+2w+(llk-8)
  bf16x8 Breg[30];
  #pragma unroll
  for (int llk = 0; llk < 10; llk++) {
    int glk = (llk < 8) ? (w * 8 + llk) : (32 + w * 2 + (llk - 8));
    #pragma unroll
    for (int gg = 0; gg < 3; gg++)
      Breg[llk * 3 + gg] = __builtin_bit_cast(bf16x8,
          *(const intx4*)(Bw + (size_t)((gg * 40 + glk) * 64 + lane) * 8));
  }
  __syncthreads();   // ghp overlays Bw: no partial writes before all hoists done

  // A-operand addressing.
  // h: slice = 2*kk + (lane>>5); elem = slice*1600 + row*16 + ((lane>>4)&1)*8
  // x: xbf + row*512*256 + t*256 + xk + (lane>>4)*8
  const int kf_x = (lane >> 4) * 8;
  int baseA[7], rowx[7];
  #pragma unroll
  for (int mt = 0; mt < 7; mt++) {
    int m = mt * 16 + (lane & 15);
    int bb = (m < 100) ? m : 99;           // clamp pad rows
    baseA[mt] = (lane >> 5) * 1600 + bb * 16 + ((lane >> 4) & 1) * 8;
    rowx[mt]  = bb * 131072;               // 512*256 shorts per row
  }

  const int* pollline = flags + (s * 4 + w) * 64;      // private per (WG, wave): 64 words
  floatx4 h4a = {0.f, 0.f, 0.f, 0.f};                  // fp32 h state in regs
  floatx4 h4b = {0.f, 0.f, 0.f, 0.f};                  // (second unit, tid<144)

  for (int t = 0; t < 512; t++) {
    const unsigned short* hrow = hist + (size_t)t * 102400;
    const unsigned short* xrow = xbf + t * 256;

    // ---- prefetch x fragments (independent of the recurrence) ----
    bf16x8 ax[2][7];
    #pragma unroll
    for (int lx = 0; lx < 2; lx++) {
      int xk = (w * 2 + lx) * 32;
      #pragma unroll
      for (int mt = 0; mt < 7; mt++)
        ax[lx][mt] = __builtin_bit_cast(bf16x8, *(const intx4*)(xrow + rowx[mt] + xk + kf_x));
    }
    asm volatile("" ::: "memory");   // keep x loads issued before the spin

    // ---- wait for this wave's k-quarter producers (64 rowgroup flags) ----
    for (;;) {
      int f = __hip_atomic_load(pollline + lane, __ATOMIC_RELAXED, __HIP_MEMORY_SCOPE_AGENT);
      if (__all(f >= t)) break;
    }
    asm volatile("" ::: "memory");   // no hoisting of h loads above the spin

    floatx4 acc[7][3];
    floatx4 accx[7];
    #pragma unroll
    for (int mt = 0; mt < 7; mt++) {
      #pragma unroll
      for (int gg = 0; gg < 3; gg++) acc[mt][gg] = floatx4{0.f, 0.f, 0.f, 0.f};
      accx[mt] = floatx4{0.f, 0.f, 0.f, 0.f};
    }

    // h-part: 8 k-steps of this wave's K-quarter
    #pragma unroll
    for (int llk = 0; llk < 8; llk++) {
      int kk = w * 8 + llk;
      #pragma unroll
      for (int mt = 0; mt < 7; mt++) {
        bf16x8 a = __builtin_bit_cast(bf16x8, *(const intx4*)(hrow + baseA[mt] + kk * 3200));
        acc[mt][0] = __builtin_amdgcn_mfma_f32_16x16x32_bf16(a, Breg[llk * 3 + 0], acc[mt][0], 0, 0, 0);
        acc[mt][1] = __builtin_amdgcn_mfma_f32_16x16x32_bf16(a, Breg[llk * 3 + 1], acc[mt][1], 0, 0, 0);
        acc[mt][2] = __builtin_amdgcn_mfma_f32_16x16x32_bf16(a, Breg[llk * 3 + 2], acc[mt][2], 0, 0, 0);
      }
    }
    // x-part: 2 k-steps (r,z join acc; n goes to accx — must stay separate)
    #pragma unroll
    for (int lx = 0; lx < 2; lx++) {
      int llk = 8 + lx;
      #pragma unroll
      for (int mt = 0; mt < 7; mt++) {
        bf16x8 a = ax[lx][mt];
        acc[mt][0] = __builtin_amdgcn_mfma_f32_16x16x32_bf16(a, Breg[llk * 3 + 0], acc[mt][0], 0, 0, 0);
        acc[mt][1] = __builtin_amdgcn_mfma_f32_16x16x32_bf16(a, Breg[llk * 3 + 1], acc[mt][1], 0, 0, 0);
        accx[mt]   = __builtin_amdgcn_mfma_f32_16x16x32_bf16(a, Breg[llk * 3 + 2], accx[mt],   0, 0, 0);
      }
    }

    // partials -> LDS: [block][col l * 20][rows at q*4] (float4 per quad)
    {
      int pb = (lane & 15) * 20 + (lane >> 4) * 4;
      #pragma unroll
      for (int mt = 0; mt < 7; mt++) {
        size_t bb = (size_t)((w * 7 + mt) * 4) * 320 + pb;
        *(floatx4*)(ghp + bb)       = acc[mt][0];
        *(floatx4*)(ghp + bb + 320) = acc[mt][1];
        *(floatx4*)(ghp + bb + 640) = acc[mt][2];
        *(floatx4*)(ghp + bb + 960) = accx[mt];
      }
    }
    bar_lds();   // (1) partials visible

    // ---- epilogue: 400 (col, row-quad) units over 256 threads ----
    gru_epi(tid, h4a, ghp, biasl, hb16);
    if (tid < 144) gru_epi(tid + 256, h4b, ghp, biasl, hb16);

    bar_lds();   // (2) hb16 visible; ghp free for next MFMA round

    // ---- every wave: store its own 25 rows write-through + ack + flags ----
    {
      unsigned long long hbase = (unsigned long long)(hist + (size_t)(t + 1) * 102400
                                                      + (size_t)s * 1600);
      if (lane < 50) {
        int row = w * 25 + (lane >> 1), half = lane & 1;
        intx4 d = *(const intx4*)(hb16 + row * 16 + half * 8);
        asm volatile("global_store_dwordx4 %0, %1, off sc0 sc1"
                     :: "v"(hbase + (unsigned long long)(row * 32 + half * 16)), "v"(d) : "memory");
      }
      if (t < 511) {
        asm volatile("s_waitcnt vmcnt(0)" ::: "memory");   // h' rows at MALL before flags
        __hip_atomic_store(flags + (lane * 4 + myq) * 64 + (s & 15) * 4 + w, t + 1,
                           __ATOMIC_RELAXED, __HIP_MEMORY_SCOPE_AGENT);
      }
    }
  }
}

// ---------------- fused time attention ----------------
// grid 1600 (one 64-col block of n'=(b*1024+d)), block 512 (8 waves).
#define ATT_LDS 68096
__global__ void __launch_bounds__(512) att_pool(
    const unsigned short* __restrict__ hist,   // slots 1..512, slice-major
    const unsigned short* __restrict__ encw,   // bf16 [512][512]
    const float* __restrict__ encb,
    float* __restrict__ vout)
{
  extern __shared__ char smem[];
  unsigned short* Bs = (unsigned short*)smem;          // [16ks][4nt][64lane][8]
  float* red  = (float*)(smem + 65536);                // [8][64]
  float* cmax = (float*)(smem + 65536 + 2048);
  float* csum = (float*)(smem + 65536 + 2048 + 256);

  const int tid = threadIdx.x, w = tid >> 6, lane = tid & 63;
  const int q = lane >> 4, col = lane & 15;
  const int n0 = blockIdx.x * 64;
  const int bA = n0 >> 10, d0 = n0 & 1023;

  // stage hs tile (slice-major gather, transposed scatter into frag layout)
  for (int ii = 0; ii < 8; ii++) {
    int c = tid + 512 * ii;
    int t = c >> 3, dd = c & 7;
    int sA = (d0 >> 4) + (dd >> 1), hsA = dd & 1;
    intx4 li = *(const intx4*)(hist + (size_t)(t + 1) * 102400
                             + (size_t)(sA * 1600 + bA * 16 + hsA * 8));
    US8 u8 = __builtin_bit_cast(US8, li);
    int kstep = t >> 5, ksub = (t >> 3) & 3, i = t & 7;
    int ntile = dd >> 1, nc0 = (dd & 1) * 8;
    unsigned short* dst = Bs + ((size_t)((kstep * 4 + ntile) * 64 + ksub * 16 + nc0)) * 8 + i;
    #pragma unroll
    for (int jj = 0; jj < 8; jj++) dst[jj * 8] = u8.u[jj];
  }
  __syncthreads();

  floatx4 acc[4][4];
  #pragma unroll
  for (int mi = 0; mi < 4; mi++)
    #pragma unroll
    for (int ni = 0; ni < 4; ni++) acc[mi][ni] = floatx4{0.f, 0.f, 0.f, 0.f};

  #pragma unroll 2
  for (int kk = 0; kk < 16; kk++) {
    int tch = kk * 32 + q * 8;
    bf16x8 af[4];
    #pragma unroll
    for (int mi = 0; mi < 4; mi++) {
      int u = (w * 4 + mi) * 16 + col;
      af[mi] = __builtin_bit_cast(bf16x8, *(const intx4*)(encw + (size_t)u * 512 + tch));
    }
    #pragma unroll
    for (int ni = 0; ni < 4; ni++) {
      bf16x8 bf = __builtin_bit_cast(bf16x8, *(const intx4*)(Bs + (size_t)((kk * 4 + ni) * 64 + lane) * 8));
      #pragma unroll
      for (int mi = 0; mi < 4; mi++)
        acc[mi][ni] = __builtin_amdgcn_mfma_f32_16x16x32_bf16(af[mi], bf, acc[mi][ni], 0, 0, 0);
    }
  }

  // + row bias
  #pragma unroll
  for (int mi = 0; mi < 4; mi++) {
    int ub = (w * 4 + mi) * 16 + q * 4;
    float b0 = encb[ub], b1 = encb[ub + 1], b2 = encb[ub + 2], b3 = encb[ub + 3];
    #pragma unroll
    for (int ni = 0; ni < 4; ni++) {
      acc[mi][ni][0] += b0; acc[mi][ni][1] += b1; acc[mi][ni][2] += b2; acc[mi][ni][3] += b3;
    }
  }
  // column max
  #pragma unroll
  for (int ni = 0; ni < 4; ni++) {
    float m = -1e30f;
    #pragma unroll
    for (int mi = 0; mi < 4; mi++)
      #pragma unroll
      for (int r = 0; r < 4; r++) m = fmaxf(m, acc[mi][ni][r]);
    m = fmaxf(m, __shfl_xor(m, 16)); m = fmaxf(m, __shfl_xor(m, 32));
    red[w * 64 + ni * 16 + col] = m;
  }
  __syncthreads();
  if (tid < 64) {
    float m = red[tid];
    for (int w2 = 1; w2 < 8; w2++) m = fmaxf(m, red[w2 * 64 + tid]);
    cmax[tid] = m;
  }
  __syncthreads();
  // exp + column sum
  #pragma unroll
  for (int ni = 0; ni < 4; ni++) {
    float cm = cmax[ni * 16 + col];
    float sum = 0.f;
    #pragma unroll
    for (int mi = 0; mi < 4; mi++)
      #pragma unroll
      for (int r = 0; r < 4; r++) {
        float e = __expf(acc[mi][ni][r] - cm);
        acc[mi][ni][r] = e; sum += e;
      }
    sum += __shfl_xor(sum, 16); sum += __shfl_xor(sum, 32);
    red[w * 64 + ni * 16 + col] = sum;
  }
  __syncthreads();
  if (tid < 64) {
    float sm = 0.f;
    for (int w2 = 0; w2 < 8; w2++) sm += red[w2 * 64 + tid];
    csum[tid] = sm;
  }
  __syncthreads();
  // weighted sum of hs
  #pragma unroll
  for (int ni = 0; ni < 4; ni++) {
    float p = 0.f;
    #pragma unroll
    for (int mi = 0; mi < 4; mi++) {
      int u0 = (w * 4 + mi) * 16 + q * 4;
      int ks = u0 >> 5, ksb = (u0 >> 3) & 3, i0 = u0 & 7;
      const unsigned short* hp = Bs + (size_t)((ks * 4 + ni) * 64 + ksb * 16 + col) * 8 + i0;
      p += acc[mi][ni][0] * bf2f(hp[0]) + acc[mi][ni][1] * bf2f(hp[1])
         + acc[mi][ni][2] * bf2f(hp[2]) + acc[mi][ni][3] * bf2f(hp[3]);
    }
    p += __shfl_xor(p, 16); p += __shfl_xor(p, 32);
    red[w * 64 + ni * 16 + col] = p;
  }
  __syncthreads();
  if (tid < 64) {
    float p = 0.f;
    for (int w2 = 0; w2 < 8; w2++) p += red[w2 * 64 + tid];
    vout[n0 + tid] = p / csum[tid];
  }
}

// ---------------- small fp32 GEMM: C(M,N) = A(M,K) @ B(N,K)^T [+bias][+relu] ----------------
__global__ void gemm_bt(const float* __restrict__ A, const float* __restrict__ B,
                        float* __restrict__ C, int M, int N, int K,
                        const float* __restrict__ bias, int relu)
{
  __shared__ float Al[16][33];
  __shared__ float Bl[64][33];
  int tx = threadIdx.x;
  int nb = blockIdx.x, mb = blockIdx.y;
  int n = nb * 64 + (tx & 63);
  int mq = tx >> 6;
  float acc[4] = {0.f, 0.f, 0.f, 0.f};
  for (int k0 = 0; k0 < K; k0 += 32) {
    for (int e = tx; e < 512; e += 256) {
      int r = e >> 5, c = e & 31; int m = mb * 16 + r;
      Al[r][c] = (m < M) ? A[(size_t)m * K + k0 + c] : 0.f;
    }
    for (int e = tx; e < 2048; e += 256) {
      int r = e >> 5, c = e & 31;
      Bl[r][c] = B[(size_t)(nb * 64 + r) * K + k0 + c];
    }
    __syncthreads();
    int nn = tx & 63;
    #pragma unroll 8
    for (int c = 0; c < 32; c++) {
      float bv = Bl[nn][c];
      #pragma unroll
      for (int i = 0; i < 4; i++) acc[i] += Al[mq * 4 + i][c] * bv;
    }
    __syncthreads();
  }
  #pragma unroll
  for (int i = 0; i < 4; i++) {
    int m = mb * 16 + mq * 4 + i;
    if (m < M && n < N) {
      float r = acc[i] + (bias ? bias[n] : 0.f);
      if (relu) r = fmaxf(r, 0.f);
      C[(size_t)m * N + n] = r;
    }
  }
}

// ---------------- GAT attention (complete graph + self loops within each block of NN nodes) ----------------
template <int NN>
__global__ void gat_att(const float* __restrict__ h, const float* __restrict__ asrc,
                        const float* __restrict__ adst, const float* __restrict__ bias,
                        float* __restrict__ out)
{
  __shared__ float asd[2][NN];
  __shared__ float P[NN][NN];
  int c = blockIdx.x, tx = threadIdx.x;
  int wid = tx >> 6, lane = tx & 63;
  for (int idx = wid; idx < 2 * NN; idx += 4) {
    int which = idx >= NN; int j = which ? idx - NN : idx;
    const float* av = which ? adst : asrc;
    float p = 0.f;
    for (int k = lane; k < 1024; k += 64) p += h[(size_t)(c * NN + j) * 1024 + k] * av[k];
    for (int m = 32; m; m >>= 1) p += __shfl_xor(p, m);
    if (lane == 0) asd[which][j] = p;
  }
  __syncthreads();
  if (tx < NN) {
    int i = tx; float mx = -1e30f; float e[NN];
    #pragma unroll
    for (int j = 0; j < NN; j++) {
      float x = asd[0][j] + asd[1][i];
      x = (x < 0.f) ? 0.2f * x : x;
      e[j] = x; mx = fmaxf(mx, x);
    }
    float s = 0.f;
    #pragma unroll
    for (int j = 0; j < NN; j++) { e[j] = __expf(e[j] - mx); s += e[j]; }
    #pragma unroll
    for (int j = 0; j < NN; j++) P[i][j] = e[j] / s;
  }
  __syncthreads();
  for (int ee = tx; ee < NN * 1024; ee += 256) {
    int i = ee >> 10, d = ee & 1023;
    float s = 0.f;
    #pragma unroll
    for (int j = 0; j < NN; j++) s += P[i][j] * h[(size_t)(c * NN + j) * 1024 + d];
    out[(size_t)(c * NN + i) * 1024 + d] = s + bias[d];
  }
}

// ---------------- stock->category pooling attention ----------------
__global__ void pool_att(const float* __restrict__ v, const float* __restrict__ pW,
                         const float* __restrict__ pb, float* __restrict__ catv)
{
  __shared__ float W[400]; __shared__ float bsh[20];
  int tx = threadIdx.x;
  for (int i = tx; i < 400; i += 256) W[i] = pW[i];
  if (tx < 20) bsh[tx] = pb[tx];
  __syncthreads();
  int gid = blockIdx.x * 256 + tx;
  int c = gid >> 10, d = gid & 1023;
  float vals[20];
  #pragma unroll
  for (int t = 0; t < 20; t++) vals[t] = v[(size_t)(c * 20 + t) * 1024 + d];
  float wv[20]; float mx = -1e30f;
  #pragma unroll
  for (int u = 0; u < 20; u++) {
    float s = bsh[u];
    #pragma unroll
    for (int t = 0; t < 20; t++) s += vals[t] * W[u * 20 + t];
    wv[u] = s; mx = fmaxf(mx, s);
  }
  float sum = 0.f, out = 0.f;
  #pragma unroll
  for (int u = 0; u < 20; u++) { float e = __expf(wv[u] - mx); sum += e; out += e * vals[u]; }
  catv[gid] = out / sum;
}

// ---------------- fusion concat ----------------
__global__ void concat_kernel(const float* __restrict__ v, const float* __restrict__ cato,
                              const float* __restrict__ iemb, float* __restrict__ F)
{
  int gid = blockIdx.x * 256 + threadIdx.x;
  if (gid < 307200) {
    int i = gid / 3072;
    int k = gid - i * 3072;
    float r;
    if (k < 1024)       r = v[(size_t)i * 1024 + k];
    else if (k < 2048)  r = cato[(size_t)(i / 20) * 1024 + (k - 1024)];
    else                r = iemb[(size_t)i * 1024 + (k - 2048)];
    F[gid] = r;
  }
}

// ---------------- output heads ----------------
__global__ void heads(const float* __restrict__ f, const float* __restrict__ rw,
                      const float* __restrict__ rb, const float* __restrict__ cw,
                      const float* __restrict__ cb, float* __restrict__ out)
{
  int b = blockIdx.x * 4 + (threadIdx.x >> 6);
  int lane = threadIdx.x & 63;
  float pr = 0.f, pc = 0.f;
  for (int k = lane; k < 1024; k += 64) {
    float x = f[(size_t)b * 1024 + k];
    pr += x * rw[k]; pc += x * cw[k];
  }
  for (int m = 32; m; m >>= 1) { pr += __shfl_xor(pr, m); pc += __shfl_xor(pc, m); }
  if (lane == 0) {
    out[b] = pr + rb[0];
    out[100 + b] = sigm(pc + cb[0]);
  }
}

// ============================================================================
extern "C" void kernel_launch(void* const* d_in, const int* in_sizes, int n_in,
                              void* d_out, int out_size, void* d_ws, size_t ws_size,
                              hipStream_t stream)
{
  const float* x     = (const float*)d_in[0];
  const float* Wih   = (const float*)d_in[1];
  const float* Whh   = (const float*)d_in[2];
  const float* bih   = (const float*)d_in[3];
  const float* bhh   = (const float*)d_in[4];
  const float* encW  = (const float*)d_in[5];
  const float* encb  = (const float*)d_in[6];
  const float* poolW = (const float*)d_in[7];
  const float* poolb = (const float*)d_in[8];
  const float* innW  = (const float*)d_in[9];
  const float* innas = (const float*)d_in[10];
  const float* innad = (const float*)d_in[11];
  const float* innb  = (const float*)d_in[12];
  const float* catW  = (const float*)d_in[13];
  const float* catas = (const float*)d_in[14];
  const float* catad = (const float*)d_in[15];
  const float* catb  = (const float*)d_in[16];
  const float* fusW  = (const float*)d_in[17];
  const float* fusb  = (const float*)d_in[18];
  const float* regW  = (const float*)d_in[19];
  const float* regb  = (const float*)d_in[20];
  const float* clsW  = (const float*)d_in[21];
  const float* clsb  = (const float*)d_in[22];
  float* out = (float*)d_out;
  char* ws = (char*)d_ws;

  unsigned short* xbf  = (unsigned short*)(ws + OF_XBF);
  unsigned short* hist = (unsigned short*)(ws + OF_HIST);
  int*            flg  = (int*)(ws + OF_FLAGS);
  unsigned short* ewbf = (unsigned short*)(ws + OF_ENCW);
  float* v    = (float*)(ws + OF_V);
  float* hin  = (float*)(ws + OF_HIN);
  float* iemb = (float*)(ws + OF_IEMB);
  float* catv = (float*)(ws + OF_CATV);
  float* cath = (float*)(ws + OF_CATH);
  float* cato = (float*)(ws + OF_CATO);
  float* fbuf = (float*)(ws + OF_FBUF);
  float* fout = (float*)(ws + OF_FOUT);

  (void)hipFuncSetAttribute((const void*)gru_recur, hipFuncAttributeMaxDynamicSharedMemorySize, GRU_LDS);
  (void)hipFuncSetAttribute((const void*)att_pool,  hipFuncAttributeMaxDynamicSharedMemorySize, ATT_LDS);

  // h(0) = 0 (slot 0) and flag reset — stream-ordered, visible at kernel dispatch
  (void)hipMemsetAsync(hist, 0, 204800, stream);
  (void)hipMemsetAsync(flg, 0, 65536, stream);

  f2bf_kernel<<<12800, 256, 0, stream>>>(x, xbf, 13107200 / 4);
  f2bf_kernel<<<256,   256, 0, stream>>>(encW, ewbf, 262144 / 4);

  gru_recur<<<64, 256, GRU_LDS, stream>>>(xbf, Whh, Wih, bih, bhh, hist, flg);
  att_pool<<<1600, 512, ATT_LDS, stream>>>(hist, ewbf, encb, v);

  gemm_bt<<<dim3(16, 7), 256, 0, stream>>>(v, innW, hin, 100, 1024, 1024, nullptr, 0);
  gat_att<20><<<5, 256, 0, stream>>>(hin, innas, innad, innb, iemb);
  pool_att<<<20, 256, 0, stream>>>(v, poolW, poolb, catv);
  gemm_bt<<<dim3(16, 1), 256, 0, stream>>>(catv, catW, cath, 5, 1024, 1024, nullptr, 0);
  gat_att<5><<<1, 256, 0, stream>>>(cath, catas, catad, catb, cato);
  concat_kernel<<<1200, 256, 0, stream>>>(v, cato, iemb, fbuf);
  gemm_bt<<<dim3(16, 7), 256, 0, stream>>>(fbuf, fusW, fout, 100, 1024, 3072, fusb, 1);
  heads<<<25, 256, 0, stream>>>(fout, regW, regb, clsW, clsb, out);

  (void)in_sizes; (void)n_in; (void)out_size; (void)ws_size;
}

// Round 4
// 4218.477 us; speedup vs baseline: 2.8933x; 2.7528x over previous
//
#include <hip/hip_runtime.h>
#include <hip/hip_bf16.h>

// ============================================================================
// CategoricalGraphAtt on MI355X.
// R9 = exact revert to R5 (best verified: gru 3104us, total 4220us).
// R6-R8 lesson: per-step time = R + W*(rows/25), R~1.3us RTT, W~4.8us per-WG
// work. Collapsing 4 groups into 1 (100 rows/WG) quadrupled W (56-load
// A-fragment batch > VGPR flight capacity -> 4-5 serial MALL RTTs) for a -1.3us
// RTT saving. The R5 shape (4 groups x 64 slices, 25 rows/WG, 16-load batch,
// single flight) is the right structure.
// GRU MALL-contention design (from R5): slice-major hist (WG's h' contiguous
// 800B, stored as 50x16B sc0sc1 dwordx4 by wave 4 via LDS repack),
// per-consumer-WG flag replication (1 poller/line), wave-4-private
// store+ack+flag tail, 2 LDS-only barriers/step.
// ============================================================================

typedef __bf16 bf16x8 __attribute__((ext_vector_type(8)));
typedef float  floatx4 __attribute__((ext_vector_type(4)));
typedef int    intx4  __attribute__((ext_vector_type(4)));

struct US8 { unsigned short u[8]; };

__device__ __forceinline__ unsigned short f2bf(float f) {
  unsigned u = __builtin_bit_cast(unsigned, f);
  u += 0x7fffu + ((u >> 16) & 1u);           // RNE
  return (unsigned short)(u >> 16);
}
__device__ __forceinline__ float bf2f(unsigned short h) {
  return __builtin_bit_cast(float, ((unsigned)h) << 16);
}
__device__ __forceinline__ float sigm(float x) { return 1.f / (1.f + __expf(-x)); }

// raw barrier: LDS-only ordering (no vmcnt drain)
__device__ __forceinline__ void bar_lds() {
  asm volatile("s_waitcnt lgkmcnt(0)" ::: "memory");
  __builtin_amdgcn_s_barrier();
  asm volatile("" ::: "memory");
}

// ---------------- workspace layout (bytes) ----------------
static const size_t OF_XBF   = 0;                 // bf16 x [100][512][256]   26,214,400
static const size_t OF_HIST  = 26214400;          // bf16 h_hist [513][256 slc][25 r][16 j] 105,062,400
static const size_t OF_ENCW  = 131277824;         // bf16 enc_att_W [512][512] 524,288
static const size_t OF_V     = 131802112;         // f32 v [100][1024]
static const size_t OF_HIN   = 132211712;         // f32 inner-GAT h
static const size_t OF_IEMB  = 132621312;         // f32 inner_emb
static const size_t OF_CATV  = 133030912;         // f32 cat_vec (pooled) [5][1024]
static const size_t OF_CATH  = 133051392;         // f32 cat-GAT h
static const size_t OF_CATO  = 133071872;         // f32 cat GAT out
static const size_t OF_FBUF  = 133092352;         // f32 fusion input [100][3072]
static const size_t OF_FOUT  = 134321152;         // f32 fusion output [100][1024]
static const size_t OF_FLAGS = 134730752;         // int flags[256 cwg][4 wave][16] = 65,536

// ---------------- fp32 -> bf16 convert ----------------
__global__ void f2bf_kernel(const float* __restrict__ src, unsigned short* __restrict__ dst, int n4) {
  int i = blockIdx.x * 256 + threadIdx.x;
  if (i < n4) {
    float4 v = ((const float4*)src)[i];
    ushort4 o;
    o.x = f2bf(v.x); o.y = f2bf(v.y); o.z = f2bf(v.z); o.w = f2bf(v.w);
    ((ushort4*)dst)[i] = o;
  }
}

// ---------------- persistent GRU recurrence ----------------
// grid 256 = 4 groups(25 rows) x 64 slices(16 j). block 320 (5 waves).
// waves 0-3: k-steps 8w..8w+8 of h-part (K=1024); wave 4: x-part (K=256) +
// the whole store/flag tail.
// hist layout per step: [slice sg(256)][row(25)][16 j] bf16 (400 shorts/slice).
// LDS: hbf_pack u32[200] @0 (overlays Bw after init) | Bw 122880 | bias @122880
//      | ghp [30][16col][20] f32 @123136 | hfp [16][25] f32 @161536.
#define GRU_LDS 163136
__global__ void __launch_bounds__(320) gru_recur(
    const unsigned short* __restrict__ xbf,
    const float* __restrict__ Whh, const float* __restrict__ Wih,
    const float* __restrict__ bih, const float* __restrict__ bhh,
    unsigned short* hist, int* flags)
{
  extern __shared__ char smem[];
  unsigned* hbf  = (unsigned*)smem;                  // [25 row][8] packed bf16 pairs
  unsigned short* Bw  = (unsigned short*)smem;       // init-only gather scratch
  float* biasl = (float*)(smem + 122880);            // [4][16]: r,z,hn,xn
  float* ghp   = (float*)(smem + 123136);            // [30 blk][16 col][20]
  float* hfp   = (float*)(smem + 161536);            // fp32 h state [16 l][25 b]

  const int tid  = threadIdx.x;
  const int lane = tid & 63;
  const int w    = tid >> 6;       // 0..4
  const int wg   = blockIdx.x;
  const int g    = wg >> 6;        // batch group 0..3
  const int s    = wg & 63;        // j slice 0..63
  const int gb   = g * 25;
  const int myq  = s >> 4;         // producer quarter

  // ---- gather B (Whh/Wih rows for this slice) into LDS in frag order ----
  for (int o = tid; o < 7680; o += 320) {
    int kk, ln; const float* sp; unsigned short* dst;
    if (o < 5120) {
      int q = o >= 2560; int rem = o - q * 2560;
      kk = rem >> 6; ln = rem & 63;
      int l = ln & 15, ksub = ln >> 4, j = s * 16 + l;
      int k = kk * 32 + ksub * 8;
      sp = (k < 1024) ? (Whh + (size_t)(q * 1024 + j) * 1024 + k)
                      : (Wih + (size_t)(q * 1024 + j) * 256 + (k - 1024));
      dst = Bw + ((size_t)((q * 40 + kk) * 64 + ln)) * 8;
    } else if (o < 7168) {
      int o2 = o - 5120; kk = o2 >> 6; ln = o2 & 63;
      int l = ln & 15, ksub = ln >> 4, j = s * 16 + l;
      sp = Whh + (size_t)(2048 + j) * 1024 + kk * 32 + ksub * 8;
      dst = Bw + (size_t)(5120 + kk * 64 + ln) * 8;
    } else {
      int o3 = o - 7168; kk = o3 >> 6; ln = o3 & 63;
      int l = ln & 15, ksub = ln >> 4, j = s * 16 + l;
      sp = Wih + (size_t)(2048 + j) * 256 + kk * 32 + ksub * 8;
      dst = Bw + (size_t)(7168 + kk * 64 + ln) * 8;
    }
    float4 f0 = *(const float4*)sp;
    float4 f1 = *(const float4*)(sp + 4);
    dst[0] = f2bf(f0.x); dst[1] = f2bf(f0.y); dst[2] = f2bf(f0.z); dst[3] = f2bf(f0.w);
    dst[4] = f2bf(f1.x); dst[5] = f2bf(f1.y); dst[6] = f2bf(f1.z); dst[7] = f2bf(f1.w);
  }
  if (tid < 16) {
    int j = s * 16 + tid;
    biasl[tid]      = bih[j]        + bhh[j];
    biasl[16 + tid] = bih[1024 + j] + bhh[1024 + j];
    biasl[32 + tid] = bhh[2048 + j];
    biasl[48 + tid] = bih[2048 + j];
  }
  for (int i = tid; i < 400; i += 320) hfp[i] = 0.f;
  __syncthreads();

  // ---- hoist B fragments (persist across all 512 steps) ----
  bf16x8 Breg[24];
  #pragma unroll
  for (int lk = 0; lk < 8; lk++) {
    int kk = w * 8 + lk;
    Breg[lk * 3 + 0] = __builtin_bit_cast(bf16x8, *(const intx4*)(Bw + (size_t)((kk)      * 64 + lane) * 8));
    Breg[lk * 3 + 1] = __builtin_bit_cast(bf16x8, *(const intx4*)(Bw + (size_t)((40 + kk) * 64 + lane) * 8));
    const unsigned short* np = (w < 4)
        ? (Bw + (size_t)(5120 + kk * 64 + lane) * 8)
        : (Bw + (size_t)(7168 + (kk - 32) * 64 + lane) * 8);
    Breg[lk * 3 + 2] = __builtin_bit_cast(bf16x8, *(const intx4*)np);
  }

  // A-operand addressing.
  // h (slice-major): sg = g*64 + 2*kk + (lane>>5); elem = sg*400 + row*16 + ((lane>>4)&1)*8
  // x (row-major): unchanged.
  const int kf_x = (lane >> 4) * 8;
  size_t baseA[2], rowx[2];
  #pragma unroll
  for (int mt = 0; mt < 2; mt++) {
    int m = mt * 16 + (lane & 15);
    int bb = (m < 25) ? m : 24;           // clamp pad rows
    baseA[mt] = (size_t)((g * 64 + (lane >> 5)) * 400 + bb * 16 + ((lane >> 4) & 1) * 8);
    rowx[mt]  = (size_t)(gb + bb) * 512 * 256;
  }

  const int* pollline = flags + (wg * 4 + w) * 16;       // private per (WG, wave)

  for (int t = 0; t < 512; t++) {
    // ---- wait for this wave's k-quarter producers (private line, no sleep) ----
    if (w < 4) {
      for (;;) {
        int f = __hip_atomic_load(pollline + (lane & 15), __ATOMIC_RELAXED, __HIP_MEMORY_SCOPE_AGENT);
        if (__all(f >= t)) break;
      }
      asm volatile("" ::: "memory");   // no hoisting of h loads above the spin
    }

    const unsigned short* hrow = hist + (size_t)t * 102400;
    floatx4 acc[2][3];
    #pragma unroll
    for (int mt = 0; mt < 2; mt++)
      #pragma unroll
      for (int gg = 0; gg < 3; gg++) acc[mt][gg] = floatx4{0.f, 0.f, 0.f, 0.f};

    #pragma unroll
    for (int lk = 0; lk < 8; lk++) {
      int kk = w * 8 + lk;
      #pragma unroll
      for (int mt = 0; mt < 2; mt++) {
        const unsigned short* ap = (w < 4)
            ? (hrow + baseA[mt] + (size_t)kk * 800)
            : (xbf + rowx[mt] + (size_t)t * 256 + (kk - 32) * 32 + kf_x);
        bf16x8 a = __builtin_bit_cast(bf16x8, *(const intx4*)ap);
        acc[mt][0] = __builtin_amdgcn_mfma_f32_16x16x32_bf16(a, Breg[lk * 3 + 0], acc[mt][0], 0, 0, 0);
        acc[mt][1] = __builtin_amdgcn_mfma_f32_16x16x32_bf16(a, Breg[lk * 3 + 1], acc[mt][1], 0, 0, 0);
        acc[mt][2] = __builtin_amdgcn_mfma_f32_16x16x32_bf16(a, Breg[lk * 3 + 2], acc[mt][2], 0, 0, 0);
      }
    }

    // partials -> LDS: [block][col l][20] with rows contiguous (float4 at q*4)
    {
      int base = (lane & 15) * 20 + (lane >> 4) * 4;
      #pragma unroll
      for (int mt = 0; mt < 2; mt++)
        #pragma unroll
        for (int gg = 0; gg < 3; gg++)
          *(floatx4*)(ghp + (size_t)((w * 2 + mt) * 3 + gg) * 320 + base) = acc[mt][gg];
    }
    bar_lds();   // (1) partials visible

    // ---- epilogue: waves 0-3, thread (lp = col-pair, b = row) ----
    if (tid < 256) {
      int lp = tid >> 5, b = tid & 31;
      if (b < 25) {
        int mt2 = b >> 4, rr = b & 15;
        unsigned packed = 0;
        #pragma unroll
        for (int ii = 0; ii < 2; ii++) {
          int l = lp * 2 + ii;
          int off = l * 20 + rr;
          float ghr = 0.f, ghz = 0.f, ghnh = 0.f, ghnx;
          #pragma unroll
          for (int ww = 0; ww < 4; ww++) {
            const float* gq = ghp + (size_t)((ww * 2 + mt2) * 3) * 320 + off;
            ghr += gq[0]; ghz += gq[320]; ghnh += gq[640];
          }
          { const float* gq = ghp + (size_t)((4 * 2 + mt2) * 3) * 320 + off;
            ghr += gq[0]; ghz += gq[320]; ghnx = gq[640]; }
          float r = sigm(ghr + biasl[l]);
          float z = sigm(ghz + biasl[16 + l]);
          float nv = ghnx + biasl[48 + l] + r * (ghnh + biasl[32 + l]);
          nv = fminf(fmaxf(nv, -15.f), 15.f);
          float e2 = __expf(-2.f * nv);
          float n = (1.f - e2) / (1.f + e2);
          float ho = hfp[l * 25 + b];
          float hn = (1.f - z) * n + z * ho;
          hfp[l * 25 + b] = hn;
          packed |= ((unsigned)f2bf(hn)) << (16 * ii);
        }
        hbf[b * 8 + lp] = packed;          // stage for wave-4 packed store
      }
    }
    bar_lds();   // (2) hbf visible to wave 4; ghp free for next MFMA round

    // ---- wave 4: contiguous 16B write-through stores + ack + flag fan-out ----
    if (w == 4) {
      if (lane < 50) {
        int b = lane >> 1, hs = lane & 1;
        intx4 d = *(const intx4*)&hbf[b * 8 + hs * 4];
        unsigned long long addr = (unsigned long long)(hist + (size_t)(t + 1) * 102400
                                  + (size_t)((g * 64 + s) * 400 + b * 16 + hs * 8));
        asm volatile("global_store_dwordx4 %0, %1, off sc0 sc1" :: "v"(addr), "v"(d) : "memory");
      }
      if (t < 511) {
        asm volatile("s_waitcnt vmcnt(0)" ::: "memory");   // h' at MALL before flags
        __hip_atomic_store(flags + ((g * 64 + lane) * 4 + myq) * 16 + (s & 15), t + 1,
                           __ATOMIC_RELAXED, __HIP_MEMORY_SCOPE_AGENT);
      }
    }
    // waves 0-3 fall through to the next poll immediately.
  }
}

// ---------------- fused time attention ----------------
// grid 1600 (one 64-col block of n'=(b*1024+d)), block 512 (8 waves).
#define ATT_LDS 68096
__global__ void __launch_bounds__(512) att_pool(
    const unsigned short* __restrict__ hist,   // slots 1..512, slice-major
    const unsigned short* __restrict__ encw,   // bf16 [512][512]
    const float* __restrict__ encb,
    float* __restrict__ vout)
{
  extern __shared__ char smem[];
  unsigned short* Bs = (unsigned short*)smem;          // [16ks][4nt][64lane][8]
  float* red  = (float*)(smem + 65536);                // [8][64]
  float* cmax = (float*)(smem + 65536 + 2048);
  float* csum = (float*)(smem + 65536 + 2048 + 256);

  const int tid = threadIdx.x, w = tid >> 6, lane = tid & 63;
  const int q = lane >> 4, col = lane & 15;
  const int n0 = blockIdx.x * 64;
  const int bg = n0 >> 10, d0 = n0 & 1023;
  const int gA = bg / 25, rA = bg - gA * 25;

  // stage hs tile (slice-major gather, transposed scatter into frag layout)
  for (int ii = 0; ii < 8; ii++) {
    int c = tid + 512 * ii;
    int t = c >> 3, dd = c & 7;
    int sA = (d0 >> 4) + (dd >> 1), hsA = dd & 1;
    intx4 li = *(const intx4*)(hist + (size_t)(t + 1) * 102400
                             + (size_t)((gA * 64 + sA) * 400 + rA * 16 + hsA * 8));
    US8 u8 = __builtin_bit_cast(US8, li);
    int kstep = t >> 5, ksub = (t >> 3) & 3, i = t & 7;
    int ntile = dd >> 1, nc0 = (dd & 1) * 8;
    unsigned short* dst = Bs + ((size_t)((kstep * 4 + ntile) * 64 + ksub * 16 + nc0)) * 8 + i;
    #pragma unroll
    for (int jj = 0; jj < 8; jj++) dst[jj * 8] = u8.u[jj];
  }
  __syncthreads();

  floatx4 acc[4][4];
  #pragma unroll
  for (int mi = 0; mi < 4; mi++)
    #pragma unroll
    for (int ni = 0; ni < 4; ni++) acc[mi][ni] = floatx4{0.f, 0.f, 0.f, 0.f};

  #pragma unroll 2
  for (int kk = 0; kk < 16; kk++) {
    int tch = kk * 32 + q * 8;
    bf16x8 af[4];
    #pragma unroll
    for (int mi = 0; mi < 4; mi++) {
      int u = (w * 4 + mi) * 16 + col;
      af[mi] = __builtin_bit_cast(bf16x8, *(const intx4*)(encw + (size_t)u * 512 + tch));
    }
    #pragma unroll
    for (int ni = 0; ni < 4; ni++) {
      bf16x8 bf = __builtin_bit_cast(bf16x8, *(const intx4*)(Bs + (size_t)((kk * 4 + ni) * 64 + lane) * 8));
      #pragma unroll
      for (int mi = 0; mi < 4; mi++)
        acc[mi][ni] = __builtin_amdgcn_mfma_f32_16x16x32_bf16(af[mi], bf, acc[mi][ni], 0, 0, 0);
    }
  }

  // + row bias
  #pragma unroll
  for (int mi = 0; mi < 4; mi++) {
    int ub = (w * 4 + mi) * 16 + q * 4;
    float b0 = encb[ub], b1 = encb[ub + 1], b2 = encb[ub + 2], b3 = encb[ub + 3];
    #pragma unroll
    for (int ni = 0; ni < 4; ni++) {
      acc[mi][ni][0] += b0; acc[mi][ni][1] += b1; acc[mi][ni][2] += b2; acc[mi][ni][3] += b3;
    }
  }
  // column max
  #pragma unroll
  for (int ni = 0; ni < 4; ni++) {
    float m = -1e30f;
    #pragma unroll
    for (int mi = 0; mi < 4; mi++)
      #pragma unroll
      for (int r = 0; r < 4; r++) m = fmaxf(m, acc[mi][ni][r]);
    m = fmaxf(m, __shfl_xor(m, 16)); m = fmaxf(m, __shfl_xor(m, 32));
    red[w * 64 + ni * 16 + col] = m;
  }
  __syncthreads();
  if (tid < 64) {
    float m = red[tid];
    for (int w2 = 1; w2 < 8; w2++) m = fmaxf(m, red[w2 * 64 + tid]);
    cmax[tid] = m;
  }
  __syncthreads();
  // exp + column sum
  #pragma unroll
  for (int ni = 0; ni < 4; ni++) {
    float cm = cmax[ni * 16 + col];
    float sum = 0.f;
    #pragma unroll
    for (int mi = 0; mi < 4; mi++)
      #pragma unroll
      for (int r = 0; r < 4; r++) {
        float e = __expf(acc[mi][ni][r] - cm);
        acc[mi][ni][r] = e; sum += e;
      }
    sum += __shfl_xor(sum, 16); sum += __shfl_xor(sum, 32);
    red[w * 64 + ni * 16 + col] = sum;
  }
  __syncthreads();
  if (tid < 64) {
    float sm = 0.f;
    for (int w2 = 0; w2 < 8; w2++) sm += red[w2 * 64 + tid];
    csum[tid] = sm;
  }
  __syncthreads();
  // weighted sum of hs
  #pragma unroll
  for (int ni = 0; ni < 4; ni++) {
    float p = 0.f;
    #pragma unroll
    for (int mi = 0; mi < 4; mi++) {
      int u0 = (w * 4 + mi) * 16 + q * 4;
      int ks = u0 >> 5, ksb = (u0 >> 3) & 3, i0 = u0 & 7;
      const unsigned short* hp = Bs + (size_t)((ks * 4 + ni) * 64 + ksb * 16 + col) * 8 + i0;
      p += acc[mi][ni][0] * bf2f(hp[0]) + acc[mi][ni][1] * bf2f(hp[1])
         + acc[mi][ni][2] * bf2f(hp[2]) + acc[mi][ni][3] * bf2f(hp[3]);
    }
    p += __shfl_xor(p, 16); p += __shfl_xor(p, 32);
    red[w * 64 + ni * 16 + col] = p;
  }
  __syncthreads();
  if (tid < 64) {
    float p = 0.f;
    for (int w2 = 0; w2 < 8; w2++) p += red[w2 * 64 + tid];
    vout[n0 + tid] = p / csum[tid];
  }
}

// ---------------- small fp32 GEMM: C(M,N) = A(M,K) @ B(N,K)^T [+bias][+relu] ----------------
__global__ void gemm_bt(const float* __restrict__ A, const float* __restrict__ B,
                        float* __restrict__ C, int M, int N, int K,
                        const float* __restrict__ bias, int relu)
{
  __shared__ float Al[16][33];
  __shared__ float Bl[64][33];
  int tx = threadIdx.x;
  int nb = blockIdx.x, mb = blockIdx.y;
  int n = nb * 64 + (tx & 63);
  int mq = tx >> 6;
  float acc[4] = {0.f, 0.f, 0.f, 0.f};
  for (int k0 = 0; k0 < K; k0 += 32) {
    for (int e = tx; e < 512; e += 256) {
      int r = e >> 5, c = e & 31; int m = mb * 16 + r;
      Al[r][c] = (m < M) ? A[(size_t)m * K + k0 + c] : 0.f;
    }
    for (int e = tx; e < 2048; e += 256) {
      int r = e >> 5, c = e & 31;
      Bl[r][c] = B[(size_t)(nb * 64 + r) * K + k0 + c];
    }
    __syncthreads();
    int nn = tx & 63;
    #pragma unroll 8
    for (int c = 0; c < 32; c++) {
      float bv = Bl[nn][c];
      #pragma unroll
      for (int i = 0; i < 4; i++) acc[i] += Al[mq * 4 + i][c] * bv;
    }
    __syncthreads();
  }
  #pragma unroll
  for (int i = 0; i < 4; i++) {
    int m = mb * 16 + mq * 4 + i;
    if (m < M && n < N) {
      float r = acc[i] + (bias ? bias[n] : 0.f);
      if (relu) r = fmaxf(r, 0.f);
      C[(size_t)m * N + n] = r;
    }
  }
}

// ---------------- GAT attention (complete graph + self loops within each block of NN nodes) ----------------
template <int NN>
__global__ void gat_att(const float* __restrict__ h, const float* __restrict__ asrc,
                        const float* __restrict__ adst, const float* __restrict__ bias,
                        float* __restrict__ out)
{
  __shared__ float asd[2][NN];
  __shared__ float P[NN][NN];
  int c = blockIdx.x, tx = threadIdx.x;
  int wid = tx >> 6, lane = tx & 63;
  for (int idx = wid; idx < 2 * NN; idx += 4) {
    int which = idx >= NN; int j = which ? idx - NN : idx;
    const float* av = which ? adst : asrc;
    float p = 0.f;
    for (int k = lane; k < 1024; k += 64) p += h[(size_t)(c * NN + j) * 1024 + k] * av[k];
    for (int m = 32; m; m >>= 1) p += __shfl_xor(p, m);
    if (lane == 0) asd[which][j] = p;
  }
  __syncthreads();
  if (tx < NN) {
    int i = tx; float mx = -1e30f; float e[NN];
    #pragma unroll
    for (int j = 0; j < NN; j++) {
      float x = asd[0][j] + asd[1][i];
      x = (x < 0.f) ? 0.2f * x : x;
      e[j] = x; mx = fmaxf(mx, x);
    }
    float s = 0.f;
    #pragma unroll
    for (int j = 0; j < NN; j++) { e[j] = __expf(e[j] - mx); s += e[j]; }
    #pragma unroll
    for (int j = 0; j < NN; j++) P[i][j] = e[j] / s;
  }
  __syncthreads();
  for (int ee = tx; ee < NN * 1024; ee += 256) {
    int i = ee >> 10, d = ee & 1023;
    float s = 0.f;
    #pragma unroll
    for (int j = 0; j < NN; j++) s += P[i][j] * h[(size_t)(c * NN + j) * 1024 + d];
    out[(size_t)(c * NN + i) * 1024 + d] = s + bias[d];
  }
}

// ---------------- stock->category pooling attention ----------------
__global__ void pool_att(const float* __restrict__ v, const float* __restrict__ pW,
                         const float* __restrict__ pb, float* __restrict__ catv)
{
  __shared__ float W[400]; __shared__ float bsh[20];
  int tx = threadIdx.x;
  for (int i = tx; i < 400; i += 256) W[i] = pW[i];
  if (tx < 20) bsh[tx] = pb[tx];
  __syncthreads();
  int gid = blockIdx.x * 256 + tx;
  int c = gid >> 10, d = gid & 1023;
  float vals[20];
  #pragma unroll
  for (int t = 0; t < 20; t++) vals[t] = v[(size_t)(c * 20 + t) * 1024 + d];
  float wv[20]; float mx = -1e30f;
  #pragma unroll
  for (int u = 0; u < 20; u++) {
    float s = bsh[u];
    #pragma unroll
    for (int t = 0; t < 20; t++) s += vals[t] * W[u * 20 + t];
    wv[u] = s; mx = fmaxf(mx, s);
  }
  float sum = 0.f, out = 0.f;
  #pragma unroll
  for (int u = 0; u < 20; u++) { float e = __expf(wv[u] - mx); sum += e; out += e * vals[u]; }
  catv[gid] = out / sum;
}

// ---------------- fusion concat ----------------
__global__ void concat_kernel(const float* __restrict__ v, const float* __restrict__ cato,
                              const float* __restrict__ iemb, float* __restrict__ F)
{
  int gid = blockIdx.x * 256 + threadIdx.x;
  if (gid < 307200) {
    int i = gid / 3072;
    int k = gid - i * 3072;
    float r;
    if (k < 1024)       r = v[(size_t)i * 1024 + k];
    else if (k < 2048)  r = cato[(size_t)(i / 20) * 1024 + (k - 1024)];
    else                r = iemb[(size_t)i * 1024 + (k - 2048)];
    F[gid] = r;
  }
}

// ---------------- output heads ----------------
__global__ void heads(const float* __restrict__ f, const float* __restrict__ rw,
                      const float* __restrict__ rb, const float* __restrict__ cw,
                      const float* __restrict__ cb, float* __restrict__ out)
{
  int b = blockIdx.x * 4 + (threadIdx.x >> 6);
  int lane = threadIdx.x & 63;
  float pr = 0.f, pc = 0.f;
  for (int k = lane; k < 1024; k += 64) {
    float x = f[(size_t)b * 1024 + k];
    pr += x * rw[k]; pc += x * cw[k];
  }
  for (int m = 32; m; m >>= 1) { pr += __shfl_xor(pr, m); pc += __shfl_xor(pc, m); }
  if (lane == 0) {
    out[b] = pr + rb[0];
    out[100 + b] = sigm(pc + cb[0]);
  }
}

// ============================================================================
extern "C" void kernel_launch(void* const* d_in, const int* in_sizes, int n_in,
                              void* d_out, int out_size, void* d_ws, size_t ws_size,
                              hipStream_t stream)
{
  const float* x     = (const float*)d_in[0];
  const float* Wih   = (const float*)d_in[1];
  const float* Whh   = (const float*)d_in[2];
  const float* bih   = (const float*)d_in[3];
  const float* bhh   = (const float*)d_in[4];
  const float* encW  = (const float*)d_in[5];
  const float* encb  = (const float*)d_in[6];
  const float* poolW = (const float*)d_in[7];
  const float* poolb = (const float*)d_in[8];
  const float* innW  = (const float*)d_in[9];
  const float* innas = (const float*)d_in[10];
  const float* innad = (const float*)d_in[11];
  const float* innb  = (const float*)d_in[12];
  const float* catW  = (const float*)d_in[13];
  const float* catas = (const float*)d_in[14];
  const float* catad = (const float*)d_in[15];
  const float* catb  = (const float*)d_in[16];
  const float* fusW  = (const float*)d_in[17];
  const float* fusb  = (const float*)d_in[18];
  const float* regW  = (const float*)d_in[19];
  const float* regb  = (const float*)d_in[20];
  const float* clsW  = (const float*)d_in[21];
  const float* clsb  = (const float*)d_in[22];
  float* out = (float*)d_out;
  char* ws = (char*)d_ws;

  unsigned short* xbf  = (unsigned short*)(ws + OF_XBF);
  unsigned short* hist = (unsigned short*)(ws + OF_HIST);
  int*            flg  = (int*)(ws + OF_FLAGS);
  unsigned short* ewbf = (unsigned short*)(ws + OF_ENCW);
  float* v    = (float*)(ws + OF_V);
  float* hin  = (float*)(ws + OF_HIN);
  float* iemb = (float*)(ws + OF_IEMB);
  float* catv = (float*)(ws + OF_CATV);
  float* cath = (float*)(ws + OF_CATH);
  float* cato = (float*)(ws + OF_CATO);
  float* fbuf = (float*)(ws + OF_FBUF);
  float* fout = (float*)(ws + OF_FOUT);

  (void)hipFuncSetAttribute((const void*)gru_recur, hipFuncAttributeMaxDynamicSharedMemorySize, GRU_LDS);
  (void)hipFuncSetAttribute((const void*)att_pool,  hipFuncAttributeMaxDynamicSharedMemorySize, ATT_LDS);

  // h(0) = 0 (slot 0) and flag reset — stream-ordered, visible at kernel dispatch
  (void)hipMemsetAsync(hist, 0, 204800, stream);
  (void)hipMemsetAsync(flg, 0, 65536, stream);

  f2bf_kernel<<<12800, 256, 0, stream>>>(x, xbf, 13107200 / 4);
  f2bf_kernel<<<256,   256, 0, stream>>>(encW, ewbf, 262144 / 4);

  gru_recur<<<256, 320, GRU_LDS, stream>>>(xbf, Whh, Wih, bih, bhh, hist, flg);
  att_pool<<<1600, 512, ATT_LDS, stream>>>(hist, ewbf, encb, v);

  gemm_bt<<<dim3(16, 7), 256, 0, stream>>>(v, innW, hin, 100, 1024, 1024, nullptr, 0);
  gat_att<20><<<5, 256, 0, stream>>>(hin, innas, innad, innb, iemb);
  pool_att<<<20, 256, 0, stream>>>(v, poolW, poolb, catv);
  gemm_bt<<<dim3(16, 1), 256, 0, stream>>>(catv, catW, cath, 5, 1024, 1024, nullptr, 0);
  gat_att<5><<<1, 256, 0, stream>>>(cath, catas, catad, catb, cato);
  concat_kernel<<<1200, 256, 0, stream>>>(v, cato, iemb, fbuf);
  gemm_bt<<<dim3(16, 7), 256, 0, stream>>>(fbuf, fusW, fout, 100, 1024, 3072, fusb, 1);
  heads<<<25, 256, 0, stream>>>(fout, regW, regb, clsW, clsb, out);

  (void)in_sizes; (void)n_in; (void)out_size; (void)ws_size;
}